// Round 8
// baseline (575.200 us; speedup 1.0000x reference)
//
#include <hip/hip_runtime.h>
#include <hip/hip_bf16.h>
#include <math.h>

typedef __hip_bfloat16 bf16;
typedef __attribute__((ext_vector_type(8))) short short8;
typedef __attribute__((ext_vector_type(4))) float floatx4;

#define HH 40
#define WW 40
#define CC 128
#define TT 8
#define NIMG 16           // B*T
#define NTOK 25600        // NIMG*HH*WW
#define MDIM 512
#define NHEAD 4
#define KVP 1608          // K/V LDS plane stride in bf16 (40*40 + 8): de-aliases ky banks

// weight-transpose buffer offsets (bf16 elems), per layer
#define WT_QKV 0
#define WT_PROJ 49152
#define WT_FC1  65536
#define WT_FC2  131072
#define WT_L    196608

// ---- input transpose via LDS tiles: x (b,c,t,y,x) -> h (n,y,x,c), both coalesced.
__global__ __launch_bounds__(256) void k_transpose_in(const float* __restrict__ x,
                                                      float* __restrict__ h) {
    int blk = blockIdx.x;
    int n = blk / 200; int r = blk % 200; int ci = r / 50, ri = r % 50;
    int b = n >> 3, t = n & 7;
    int c0 = ci * 32, r0 = ri * 32;
    __shared__ float tile[32][33];
    int tid = threadIdx.x;
    int lc = tid >> 5, lr = tid & 31;         // 8 x 32
    #pragma unroll
    for (int it = 0; it < 4; ++it) {
        int cc = it * 8 + lc;
        tile[cc][lr] = x[((size_t)((b * 128 + c0 + cc) * 8 + t)) * 1600 + r0 + lr];
    }
    __syncthreads();
    #pragma unroll
    for (int it = 0; it < 4; ++it) {
        int rr = it * 8 + lc;
        h[((size_t)(n * 1600 + r0 + rr)) * 128 + c0 + lr] = tile[lr][rr];
    }
}

// ---- weight convert+transpose: W[K,N] fp32 -> Wt[N,K] bf16, 64x64 LDS tiles.
__global__ __launch_bounds__(256) void k_wt(const float* __restrict__ qkv_w,
                                            const float* __restrict__ proj_w,
                                            const float* __restrict__ fc1_w,
                                            const float* __restrict__ fc2_w,
                                            bf16* __restrict__ wt) {
    __shared__ float tile[64][65];
    int id = blockIdx.x;
    int l = id / 48, r = id % 48;
    const float* src; bf16* dst; int K_, N_, t;
    if (r < 12)      { src = qkv_w  + l * 128 * 384; dst = wt + l * WT_L + WT_QKV; K_ = 128; N_ = 384; t = r; }
    else if (r < 16) { src = proj_w + l * 128 * 128; dst = wt + l * WT_L + WT_PROJ; K_ = 128; N_ = 128; t = r - 12; }
    else if (r < 32) { src = fc1_w  + l * 128 * 512; dst = wt + l * WT_L + WT_FC1; K_ = 128; N_ = 512; t = r - 16; }
    else             { src = fc2_w  + l * 512 * 128; dst = wt + l * WT_L + WT_FC2; K_ = 512; N_ = 128; t = r - 32; }
    int KT = K_ >> 6;
    int k0 = (t % KT) * 64, n0 = (t / KT) * 64;
    int tid = threadIdx.x;
    for (int c = tid; c < 4096; c += 256) {
        int kk = c >> 6, nn = c & 63;
        tile[kk][nn] = src[(size_t)(k0 + kk) * N_ + n0 + nn];
    }
    __syncthreads();
    for (int c = tid; c < 4096; c += 256) {
        int nn = c >> 6, kk = c & 63;
        dst[(size_t)(n0 + nn) * K_ + k0 + kk] = __float2bfloat16(tile[kk][nn]);
    }
}

// ---- fused LayerNorm + MFMA GEMM: D = LN(A) @ Bt^T + bias. K=128 fixed.
template<typename OutT>
__global__ __launch_bounds__(256) void k_lngemm(const float* __restrict__ A,   // [M][128] fp32
                                                const bf16* __restrict__ Bt,   // [N][128] bf16
                                                const float* __restrict__ g,
                                                const float* __restrict__ be,
                                                const float* __restrict__ bias,
                                                OutT* __restrict__ D,
                                                int N) {
    constexpr int LDK = 40;
    __shared__ bf16 As[128 * LDK];
    __shared__ bf16 Bs[128 * LDK];
    __shared__ float sMean[128], sRstd[128], sG[128], sB[128];
    int tid = threadIdx.x;
    int m0 = blockIdx.y * 128, n0 = blockIdx.x * 128;
    {
        int row = tid >> 1, half = tid & 1;
        const float* p = A + (size_t)(m0 + row) * 128 + half * 64;
        float s = 0.f, q = 0.f;
        #pragma unroll
        for (int i = 0; i < 64; i += 4) {
            float4 f = *(const float4*)(p + i);
            s += f.x + f.y + f.z + f.w;
            q += f.x * f.x + f.y * f.y + f.z * f.z + f.w * f.w;
        }
        s += __shfl_xor(s, 1); q += __shfl_xor(q, 1);
        if (half == 0) {
            float mean = s * (1.0f / 128.0f);
            float var = q * (1.0f / 128.0f) - mean * mean;
            sMean[row] = mean;
            sRstd[row] = rsqrtf(var + 1e-5f);
        }
        if (tid < 128) { sG[tid] = g[tid]; sB[tid] = be[tid]; }
    }
    __syncthreads();
    int wave = tid >> 6, lane = tid & 63;
    int l15 = lane & 15, quad = lane >> 4;
    int wr = wave >> 1, wc = wave & 1;
    floatx4 acc[4][4];
    #pragma unroll
    for (int i = 0; i < 4; ++i)
        #pragma unroll
        for (int j = 0; j < 4; ++j)
            acc[i][j] = (floatx4){0.f, 0.f, 0.f, 0.f};

    for (int k0 = 0; k0 < 128; k0 += 32) {
        #pragma unroll
        for (int it = 0; it < 4; ++it) {
            int c = tid + it * 256;
            int row = c >> 3, kq = (c & 7) * 4;
            float4 f = *(const float4*)(A + (size_t)(m0 + row) * 128 + k0 + kq);
            float mean = sMean[row], rst = sRstd[row];
            float r0v = (f.x - mean) * rst * sG[k0 + kq]     + sB[k0 + kq];
            float r1v = (f.y - mean) * rst * sG[k0 + kq + 1] + sB[k0 + kq + 1];
            float r2v = (f.z - mean) * rst * sG[k0 + kq + 2] + sB[k0 + kq + 2];
            float r3v = (f.w - mean) * rst * sG[k0 + kq + 3] + sB[k0 + kq + 3];
            __hip_bfloat162 p0, p1;
            p0.x = __float2bfloat16(r0v); p0.y = __float2bfloat16(r1v);
            p1.x = __float2bfloat16(r2v); p1.y = __float2bfloat16(r3v);
            *(__hip_bfloat162*)&As[row * LDK + kq]     = p0;
            *(__hip_bfloat162*)&As[row * LDK + kq + 2] = p1;
        }
        #pragma unroll
        for (int c = tid; c < 512; c += 256) {
            int row = c >> 2, off = (c & 3) * 8;
            *(uint4*)&Bs[row * LDK + off] =
                *(const uint4*)&Bt[(size_t)(n0 + row) * 128 + k0 + off];
        }
        __syncthreads();
        short8 af[4], bfr[4];
        #pragma unroll
        for (int i = 0; i < 4; ++i)
            af[i] = *(const short8*)&As[(wr * 64 + i * 16 + l15) * LDK + quad * 8];
        #pragma unroll
        for (int j = 0; j < 4; ++j)
            bfr[j] = *(const short8*)&Bs[(wc * 64 + j * 16 + l15) * LDK + quad * 8];
        #pragma unroll
        for (int i = 0; i < 4; ++i)
            #pragma unroll
            for (int j = 0; j < 4; ++j)
                acc[i][j] = __builtin_amdgcn_mfma_f32_16x16x32_bf16(af[i], bfr[j], acc[i][j], 0, 0, 0);
        __syncthreads();
    }
    #pragma unroll
    for (int i = 0; i < 4; ++i) {
        #pragma unroll
        for (int j = 0; j < 4; ++j) {
            int nn = n0 + wc * 64 + j * 16 + l15;
            float bv = bias[nn];
            #pragma unroll
            for (int rg = 0; rg < 4; ++rg) {
                int m = m0 + wr * 64 + i * 16 + quad * 4 + rg;
                float v = acc[i][j][rg] + bv;
                if constexpr (sizeof(OutT) == 2)
                    D[(size_t)m * N + nn] = __float2bfloat16(v);
                else
                    D[(size_t)m * N + nn] = v;
            }
        }
    }
}

// ---- MFMA bf16 GEMM: D[M,N] = A[M,K] @ Bt[N,K]^T + bias (+R).
template<int BM, int BN, int WM, int WN, typename OutT>
__global__ __launch_bounds__(256) void k_gemm_mfma(const bf16* __restrict__ A,
                                                   const bf16* __restrict__ Bt,
                                                   const float* __restrict__ bias,
                                                   const float* __restrict__ R,
                                                   OutT* __restrict__ D,
                                                   int K, int N) {
    constexpr int LDK = 40;
    __shared__ bf16 As[BM * LDK];
    __shared__ bf16 Bs[BN * LDK];
    int tid = threadIdx.x;
    int wave = tid >> 6, lane = tid & 63;
    int l15 = lane & 15, quad = lane >> 4;
    constexpr int WCOLS = BN / WN;
    int wr = wave / WCOLS, wc = wave % WCOLS;
    int m0 = blockIdx.y * BM, n0 = blockIdx.x * BN;
    constexpr int MI = WM / 16, NJ = WN / 16;
    floatx4 acc[MI][NJ];
    #pragma unroll
    for (int i = 0; i < MI; ++i)
        #pragma unroll
        for (int j = 0; j < NJ; ++j)
            acc[i][j] = (floatx4){0.f, 0.f, 0.f, 0.f};

    for (int k0 = 0; k0 < K; k0 += 32) {
        #pragma unroll
        for (int c = tid; c < BM * 4; c += 256) {
            int row = c >> 2, off = (c & 3) * 8;
            *(uint4*)&As[row * LDK + off] =
                *(const uint4*)&A[(size_t)(m0 + row) * K + k0 + off];
        }
        #pragma unroll
        for (int c = tid; c < BN * 4; c += 256) {
            int row = c >> 2, off = (c & 3) * 8;
            *(uint4*)&Bs[row * LDK + off] =
                *(const uint4*)&Bt[(size_t)(n0 + row) * K + k0 + off];
        }
        __syncthreads();
        short8 af[MI], bfr[NJ];
        #pragma unroll
        for (int i = 0; i < MI; ++i)
            af[i] = *(const short8*)&As[(wr * WM + i * 16 + l15) * LDK + quad * 8];
        #pragma unroll
        for (int j = 0; j < NJ; ++j)
            bfr[j] = *(const short8*)&Bs[(wc * WN + j * 16 + l15) * LDK + quad * 8];
        #pragma unroll
        for (int i = 0; i < MI; ++i)
            #pragma unroll
            for (int j = 0; j < NJ; ++j)
                acc[i][j] = __builtin_amdgcn_mfma_f32_16x16x32_bf16(af[i], bfr[j], acc[i][j], 0, 0, 0);
        __syncthreads();
    }
    #pragma unroll
    for (int i = 0; i < MI; ++i) {
        #pragma unroll
        for (int j = 0; j < NJ; ++j) {
            int nn = n0 + wc * WN + j * 16 + l15;
            float bv = bias[nn];
            #pragma unroll
            for (int rg = 0; rg < 4; ++rg) {
                int m = m0 + wr * WM + i * 16 + quad * 4 + rg;
                float v = acc[i][j][rg] + bv;
                if (R) v += R[(size_t)m * N + nn];
                if constexpr (sizeof(OutT) == 2)
                    D[(size_t)m * N + nn] = __float2bfloat16(v);
                else
                    D[(size_t)m * N + nn] = v;
            }
        }
    }
}

// ---- row-tiled 7x7 neighborhood attention; per-(xq,ky) logits, q in registers.
__global__ __launch_bounds__(256) void k_attn(const bf16* __restrict__ qkv,
                                              const float* __restrict__ rpb,
                                              bf16* __restrict__ out) {
    int blk = blockIdx.x;            // ((n*40 + y)*4 + head)
    int head = blk & 3;
    int ny = blk >> 2;
    int n = ny / 40, y = ny % 40;
    int sy = min(max(y - 3, 0), HH - 7);
    __shared__ bf16 qsb[40][40];     // unscaled q, bf16 (3.2 KB; stride 80 B, 16B-aligned)
    __shared__ bf16 KVs[7 * KVP];    // K then V, plane stride 1608 (22.5 KB)
    __shared__ float lg[40][49];     // 7.8 KB
    int tid = threadIdx.x;
    // q staging: raw copy, 160 uint4
    if (tid < 160) {
        int xq = tid >> 2, d8 = (tid & 3) * 8;
        *(uint4*)&qsb[xq][d8] =
            *(const uint4*)(qkv + ((size_t)(n * 1600 + y * 40 + xq)) * 384 + head * 32 + d8);
    }
    // phase 1: K window
    for (int i2 = tid; i2 < 1120; i2 += 256) {     // 7*40*4
        int d8 = i2 & 3, kx = (i2 >> 2) % 40, ky = i2 / 160;
        size_t base = ((size_t)(n * 1600 + (sy + ky) * 40 + kx)) * 384 + 128 + head * 32 + d8 * 8;
        *(uint4*)&KVs[ky * KVP + kx * 40 + d8 * 8] = *(const uint4*)(qkv + base);
    }
    __syncthreads();
    // logits: one thread per (xq, ky); q unpacked once, 7 keys per thread
    for (int p2 = tid; p2 < 280; p2 += 256) {
        int xq = p2 / 7, ky = p2 - (p2 / 7) * 7;
        int sx = min(max(xq - 3, 0), WW - 7);
        float qf[32];
        const __hip_bfloat162* qp = (const __hip_bfloat162*)&qsb[xq][0];
        #pragma unroll
        for (int c = 0; c < 16; ++c) {
            float2 f = __bfloat1622float2(qp[c]);
            qf[2 * c] = f.x; qf[2 * c + 1] = f.y;
        }
        const float* rb = rpb + head * 169 + (sy + ky - y + 6) * 13 + (sx - xq + 6);
        int kbase = ky * KVP + sx * 40;
        #pragma unroll
        for (int jx = 0; jx < 7; ++jx) {
            const __hip_bfloat162* kp = (const __hip_bfloat162*)&KVs[kbase + jx * 40];
            float dot = 0.f;
            #pragma unroll
            for (int c = 0; c < 16; ++c) {
                float2 kv = __bfloat1622float2(kp[c]);
                dot += qf[2 * c] * kv.x + qf[2 * c + 1] * kv.y;
            }
            lg[xq][ky * 7 + jx] = dot * 0.1767766952966369f + rb[jx];
        }
    }
    __syncthreads();                               // K reads done
    // phase 2: overwrite with V; softmax concurrently (disjoint LDS)
    for (int i2 = tid; i2 < 1120; i2 += 256) {
        int d8 = i2 & 3, kx = (i2 >> 2) % 40, ky = i2 / 160;
        size_t base = ((size_t)(n * 1600 + (sy + ky) * 40 + kx)) * 384 + 256 + head * 32 + d8 * 8;
        *(uint4*)&KVs[ky * KVP + kx * 40 + d8 * 8] = *(const uint4*)(qkv + base);
    }
    if (tid < 40) {
        float m = -1e30f;
        for (int j = 0; j < 49; ++j) m = fmaxf(m, lg[tid][j]);
        float s = 0.f;
        for (int j = 0; j < 49; ++j) { float e = expf(lg[tid][j] - m); lg[tid][j] = e; s += e; }
        float inv = 1.0f / s;
        for (int j = 0; j < 49; ++j) lg[tid][j] *= inv;
    }
    __syncthreads();
    // PV reduce: 2 channels per thread
    for (int o = tid; o < 640; o += 256) {
        int xq = o >> 4, dp = (o & 15) * 2;
        int sx = min(max(xq - 3, 0), WW - 7);
        float a0 = 0.f, a1 = 0.f;
        #pragma unroll
        for (int ky = 0; ky < 7; ++ky) {
            int vbase = ky * KVP + sx * 40 + dp;
            #pragma unroll
            for (int jx = 0; jx < 7; ++jx) {
                float p = lg[xq][ky * 7 + jx];
                float2 v = __bfloat1622float2(*(const __hip_bfloat162*)&KVs[vbase + jx * 40]);
                a0 += p * v.x; a1 += p * v.y;
            }
        }
        __hip_bfloat162 o2;
        o2.x = __float2bfloat16(a0); o2.y = __float2bfloat16(a1);
        *(__hip_bfloat162*)(out + ((size_t)(n * 1600 + y * 40 + xq)) * 128 + head * 32 + dp) = o2;
    }
}

// ---- depthwise 3x3x3 conv + bias + exact GELU; bf16 in/out, fp32 math.
// 512 scalar-channel threads, x split in halves: 1280 blocks.
__global__ __launch_bounds__(512) void k_dwconv(const bf16* __restrict__ inp,   // [16][1600][512] bf16
                                                const float* __restrict__ w,
                                                const float* __restrict__ bias,
                                                bf16* __restrict__ outp) {
    int blk = blockIdx.x;            // (n*40 + y)*2 + xh
    int xh = blk & 1;
    int ny = blk >> 1;
    int n = ny / 40, y = ny - n * 40;
    int b = n >> 3, t = n & 7;
    int m = threadIdx.x;
    float wr[27];
    #pragma unroll
    for (int i = 0; i < 27; ++i) wr[i] = w[i * 512 + m];
    float bs = bias[m];
    const bf16* rp[9];
    #pragma unroll
    for (int dt = 0; dt < 3; ++dt)
        #pragma unroll
        for (int dy = 0; dy < 3; ++dy) {
            int tt = t + dt - 1, yy = y + dy - 1;
            bool v = (tt >= 0 && tt < 8 && yy >= 0 && yy < 40);
            rp[dt * 3 + dy] = v ? inp + ((size_t)((b * 8 + tt) * 1600 + yy * 40)) * 512 + m
                                : nullptr;
        }
    int x0 = xh * 20;
    float c0[9], c1[9], c2[9];
    #pragma unroll
    for (int p = 0; p < 9; ++p) {
        c0[p] = (x0 > 0 && rp[p]) ? __bfloat162float(rp[p][(size_t)(x0 - 1) * 512]) : 0.f;
        c1[p] = rp[p] ? __bfloat162float(rp[p][(size_t)x0 * 512]) : 0.f;
    }
    size_t outbase = ((size_t)(n * 1600 + y * 40)) * 512 + m;
    for (int x = x0; x < x0 + 20; ++x) {
        #pragma unroll
        for (int p = 0; p < 9; ++p)
            c2[p] = (x < 39 && rp[p]) ? __bfloat162float(rp[p][(size_t)(x + 1) * 512]) : 0.f;
        float acc = bs;
        #pragma unroll
        for (int p = 0; p < 9; ++p)
            acc += wr[p * 3 + 0] * c0[p] + wr[p * 3 + 1] * c1[p] + wr[p * 3 + 2] * c2[p];
        float g = 0.5f * acc * (1.0f + erff(acc * 0.70710678118654752f));
        outp[outbase + (size_t)x * 512] = __float2bfloat16(g);
        #pragma unroll
        for (int p = 0; p < 9; ++p) { c0[p] = c1[p]; c1[p] = c2[p]; }
    }
}

// ---- final LN + transpose via LDS tile, coalesced stores.
__global__ __launch_bounds__(256) void k_ln_out(const float* __restrict__ src,
                                                const float* __restrict__ gamma,
                                                const float* __restrict__ beta,
                                                float* __restrict__ out) {
    int blk = blockIdx.x;
    int n = blk / 50, ri = blk % 50;
    int r0 = ri * 32;
    int b = n >> 3, t = n & 7;
    __shared__ float tile[128][33];
    int tid = threadIdx.x;
    int tok = tid >> 3, sub = tid & 7;
    const float* sp = src + ((size_t)(n * 1600 + r0 + tok)) * 128 + sub * 16;
    float v[16];
    float s = 0.f, q = 0.f;
    #pragma unroll
    for (int i = 0; i < 16; i += 4) {
        float4 f = *(const float4*)(sp + i);
        v[i] = f.x; v[i + 1] = f.y; v[i + 2] = f.z; v[i + 3] = f.w;
        s += f.x + f.y + f.z + f.w;
        q += f.x * f.x + f.y * f.y + f.z * f.z + f.w * f.w;
    }
    #pragma unroll
    for (int o = 4; o > 0; o >>= 1) { s += __shfl_xor(s, o); q += __shfl_xor(q, o); }
    float mean = s * (1.0f / 128.0f);
    float var = q * (1.0f / 128.0f) - mean * mean;
    float inv = rsqrtf(var + 1e-5f);
    #pragma unroll
    for (int i = 0; i < 16; ++i) {
        int ch = sub * 16 + i;
        tile[ch][tok] = (v[i] - mean) * inv * gamma[ch] + beta[ch];
    }
    __syncthreads();
    #pragma unroll
    for (int it = 0; it < 16; ++it) {
        int idx = it * 256 + tid;
        int ch = idx >> 5, tk = idx & 31;
        out[((size_t)((b * 128 + ch) * 8 + t)) * 1600 + r0 + tk] = tile[ch][tk];
    }
}

extern "C" void kernel_launch(void* const* d_in, const int* in_sizes, int n_in,
                              void* d_out, int out_size, void* d_ws, size_t ws_size,
                              hipStream_t stream) {
    const float* x      = (const float*)d_in[0];
    const float* ln1_g  = (const float*)d_in[1];
    const float* ln1_b  = (const float*)d_in[2];
    const float* qkv_w  = (const float*)d_in[3];
    const float* qkv_b  = (const float*)d_in[4];
    const float* rpb    = (const float*)d_in[5];
    const float* proj_w = (const float*)d_in[6];
    const float* proj_b = (const float*)d_in[7];
    const float* ln2_g  = (const float*)d_in[8];
    const float* ln2_b  = (const float*)d_in[9];
    const float* fc1_w  = (const float*)d_in[10];
    const float* fc1_b  = (const float*)d_in[11];
    const float* dw_w   = (const float*)d_in[12];
    const float* dw_b   = (const float*)d_in[13];
    const float* fc2_w  = (const float*)d_in[14];
    const float* fc2_b  = (const float*)d_in[15];
    const float* out_g  = (const float*)d_in[16];
    const float* out_b  = (const float*)d_in[17];
    float* out = (float*)d_out;

    // workspace: h f32 | f1 bf16 | qkvb bf16 | f2b bf16 | abuf bf16 | wt bf16
    float* h    = (float*)d_ws;
    bf16* f1    = (bf16*)(h + (size_t)NTOK * 128);
    bf16* qkvb  = f1   + (size_t)NTOK * 512;
    bf16* f2b   = qkvb + (size_t)NTOK * 384;
    bf16* abuf  = f2b  + (size_t)NTOK * 512;
    bf16* wt    = abuf + (size_t)NTOK * 128;

    k_wt<<<96, 256, 0, stream>>>(qkv_w, proj_w, fc1_w, fc2_w, wt);
    k_transpose_in<<<NIMG * 200, 256, 0, stream>>>(x, h);
    for (int l = 0; l < 2; ++l) {
        const bf16* wtl = wt + (size_t)l * WT_L;
        k_lngemm<bf16><<<dim3(3, 200), 256, 0, stream>>>(
            h, wtl + WT_QKV, ln1_g + l * 128, ln1_b + l * 128, qkv_b + l * 384, qkvb, 384);
        k_attn<<<NIMG * HH * NHEAD, 256, 0, stream>>>(qkvb, rpb + l * 4 * 169, abuf);
        k_gemm_mfma<64, 128, 32, 64, float><<<dim3(1, 400), 256, 0, stream>>>(
            abuf, wtl + WT_PROJ, proj_b + l * 128, h, h, 128, 128);
        k_lngemm<bf16><<<dim3(4, 200), 256, 0, stream>>>(
            h, wtl + WT_FC1, ln2_g + l * 128, ln2_b + l * 128, fc1_b + l * 512, f1, 512);
        k_dwconv<<<NIMG * HH * 2, 512, 0, stream>>>(f1, dw_w + l * 27 * 512, dw_b + l * 512, f2b);
        k_gemm_mfma<64, 128, 32, 64, float><<<dim3(1, 400), 256, 0, stream>>>(
            f2b, wtl + WT_FC2, fc2_b + l * 128, h, h, 512, 128);
    }
    k_ln_out<<<NIMG * 50, 256, 0, stream>>>(h, out_g, out_b, out);
}

// Round 9
// 457.645 us; speedup vs baseline: 1.2569x; 1.2569x over previous
//
#include <hip/hip_runtime.h>
#include <hip/hip_bf16.h>
#include <math.h>

typedef __hip_bfloat16 bf16;
typedef __attribute__((ext_vector_type(8))) short short8;
typedef __attribute__((ext_vector_type(4))) float floatx4;

#define HH 40
#define WW 40
#define CC 128
#define TT 8
#define NIMG 16           // B*T
#define NTOK 25600        // NIMG*HH*WW
#define MDIM 512
#define NHEAD 4
#define KVP 1608          // K/V LDS plane stride in bf16 (40*40 + 8)

// weight-transpose buffer offsets (bf16 elems), per layer
#define WT_QKV 0
#define WT_PROJ 49152
#define WT_FC1  65536
#define WT_FC2  131072
#define WT_L    196608

// ---- input transpose via LDS tiles: x (b,c,t,y,x) -> h (n,y,x,c), both coalesced.
__global__ __launch_bounds__(256) void k_transpose_in(const float* __restrict__ x,
                                                      float* __restrict__ h) {
    int blk = blockIdx.x;
    int n = blk / 200; int r = blk % 200; int ci = r / 50, ri = r % 50;
    int b = n >> 3, t = n & 7;
    int c0 = ci * 32, r0 = ri * 32;
    __shared__ float tile[32][33];
    int tid = threadIdx.x;
    int lc = tid >> 5, lr = tid & 31;         // 8 x 32
    #pragma unroll
    for (int it = 0; it < 4; ++it) {
        int cc = it * 8 + lc;
        tile[cc][lr] = x[((size_t)((b * 128 + c0 + cc) * 8 + t)) * 1600 + r0 + lr];
    }
    __syncthreads();
    #pragma unroll
    for (int it = 0; it < 4; ++it) {
        int rr = it * 8 + lc;
        h[((size_t)(n * 1600 + r0 + rr)) * 128 + c0 + lr] = tile[lr][rr];
    }
}

// ---- weight convert+transpose: W[K,N] fp32 -> Wt[N,K] bf16, 64x64 LDS tiles.
__global__ __launch_bounds__(256) void k_wt(const float* __restrict__ qkv_w,
                                            const float* __restrict__ proj_w,
                                            const float* __restrict__ fc1_w,
                                            const float* __restrict__ fc2_w,
                                            bf16* __restrict__ wt) {
    __shared__ float tile[64][65];
    int id = blockIdx.x;
    int l = id / 48, r = id % 48;
    const float* src; bf16* dst; int K_, N_, t;
    if (r < 12)      { src = qkv_w  + l * 128 * 384; dst = wt + l * WT_L + WT_QKV; K_ = 128; N_ = 384; t = r; }
    else if (r < 16) { src = proj_w + l * 128 * 128; dst = wt + l * WT_L + WT_PROJ; K_ = 128; N_ = 128; t = r - 12; }
    else if (r < 32) { src = fc1_w  + l * 128 * 512; dst = wt + l * WT_L + WT_FC1; K_ = 128; N_ = 512; t = r - 16; }
    else             { src = fc2_w  + l * 512 * 128; dst = wt + l * WT_L + WT_FC2; K_ = 512; N_ = 128; t = r - 32; }
    int KT = K_ >> 6;
    int k0 = (t % KT) * 64, n0 = (t / KT) * 64;
    int tid = threadIdx.x;
    for (int c = tid; c < 4096; c += 256) {
        int kk = c >> 6, nn = c & 63;
        tile[kk][nn] = src[(size_t)(k0 + kk) * N_ + n0 + nn];
    }
    __syncthreads();
    for (int c = tid; c < 4096; c += 256) {
        int nn = c >> 6, kk = c & 63;
        dst[(size_t)(n0 + nn) * K_ + k0 + kk] = __float2bfloat16(tile[kk][nn]);
    }
}

// ---- fused LayerNorm + MFMA GEMM: D = LN(A) @ Bt^T + bias. K=128 fixed.
template<typename OutT>
__global__ __launch_bounds__(256) void k_lngemm(const float* __restrict__ A,   // [M][128] fp32
                                                const bf16* __restrict__ Bt,   // [N][128] bf16
                                                const float* __restrict__ g,
                                                const float* __restrict__ be,
                                                const float* __restrict__ bias,
                                                OutT* __restrict__ D,
                                                int N) {
    constexpr int LDK = 40;
    __shared__ bf16 As[128 * LDK];
    __shared__ bf16 Bs[128 * LDK];
    __shared__ float sMean[128], sRstd[128], sG[128], sB[128];
    int tid = threadIdx.x;
    int m0 = blockIdx.y * 128, n0 = blockIdx.x * 128;
    {
        int row = tid >> 1, half = tid & 1;
        const float* p = A + (size_t)(m0 + row) * 128 + half * 64;
        float s = 0.f, q = 0.f;
        #pragma unroll
        for (int i = 0; i < 64; i += 4) {
            float4 f = *(const float4*)(p + i);
            s += f.x + f.y + f.z + f.w;
            q += f.x * f.x + f.y * f.y + f.z * f.z + f.w * f.w;
        }
        s += __shfl_xor(s, 1); q += __shfl_xor(q, 1);
        if (half == 0) {
            float mean = s * (1.0f / 128.0f);
            float var = q * (1.0f / 128.0f) - mean * mean;
            sMean[row] = mean;
            sRstd[row] = rsqrtf(var + 1e-5f);
        }
        if (tid < 128) { sG[tid] = g[tid]; sB[tid] = be[tid]; }
    }
    __syncthreads();
    int wave = tid >> 6, lane = tid & 63;
    int l15 = lane & 15, quad = lane >> 4;
    int wr = wave >> 1, wc = wave & 1;
    floatx4 acc[4][4];
    #pragma unroll
    for (int i = 0; i < 4; ++i)
        #pragma unroll
        for (int j = 0; j < 4; ++j)
            acc[i][j] = (floatx4){0.f, 0.f, 0.f, 0.f};

    for (int k0 = 0; k0 < 128; k0 += 32) {
        #pragma unroll
        for (int it = 0; it < 4; ++it) {
            int c = tid + it * 256;
            int row = c >> 3, kq = (c & 7) * 4;
            float4 f = *(const float4*)(A + (size_t)(m0 + row) * 128 + k0 + kq);
            float mean = sMean[row], rst = sRstd[row];
            float r0v = (f.x - mean) * rst * sG[k0 + kq]     + sB[k0 + kq];
            float r1v = (f.y - mean) * rst * sG[k0 + kq + 1] + sB[k0 + kq + 1];
            float r2v = (f.z - mean) * rst * sG[k0 + kq + 2] + sB[k0 + kq + 2];
            float r3v = (f.w - mean) * rst * sG[k0 + kq + 3] + sB[k0 + kq + 3];
            __hip_bfloat162 p0, p1;
            p0.x = __float2bfloat16(r0v); p0.y = __float2bfloat16(r1v);
            p1.x = __float2bfloat16(r2v); p1.y = __float2bfloat16(r3v);
            *(__hip_bfloat162*)&As[row * LDK + kq]     = p0;
            *(__hip_bfloat162*)&As[row * LDK + kq + 2] = p1;
        }
        #pragma unroll
        for (int c = tid; c < 512; c += 256) {
            int row = c >> 2, off = (c & 3) * 8;
            *(uint4*)&Bs[row * LDK + off] =
                *(const uint4*)&Bt[(size_t)(n0 + row) * 128 + k0 + off];
        }
        __syncthreads();
        short8 af[4], bfr[4];
        #pragma unroll
        for (int i = 0; i < 4; ++i)
            af[i] = *(const short8*)&As[(wr * 64 + i * 16 + l15) * LDK + quad * 8];
        #pragma unroll
        for (int j = 0; j < 4; ++j)
            bfr[j] = *(const short8*)&Bs[(wc * 64 + j * 16 + l15) * LDK + quad * 8];
        #pragma unroll
        for (int i = 0; i < 4; ++i)
            #pragma unroll
            for (int j = 0; j < 4; ++j)
                acc[i][j] = __builtin_amdgcn_mfma_f32_16x16x32_bf16(af[i], bfr[j], acc[i][j], 0, 0, 0);
        __syncthreads();
    }
    #pragma unroll
    for (int i = 0; i < 4; ++i) {
        #pragma unroll
        for (int j = 0; j < 4; ++j) {
            int nn = n0 + wc * 64 + j * 16 + l15;
            float bv = bias[nn];
            #pragma unroll
            for (int rg = 0; rg < 4; ++rg) {
                int m = m0 + wr * 64 + i * 16 + quad * 4 + rg;
                float v = acc[i][j][rg] + bv;
                if constexpr (sizeof(OutT) == 2)
                    D[(size_t)m * N + nn] = __float2bfloat16(v);
                else
                    D[(size_t)m * N + nn] = v;
            }
        }
    }
}

// ---- MFMA bf16 GEMM: D[M,N] = A[M,K] @ Bt[N,K]^T + bias (+R).
template<int BM, int BN, int WM, int WN, typename OutT>
__global__ __launch_bounds__(256) void k_gemm_mfma(const bf16* __restrict__ A,
                                                   const bf16* __restrict__ Bt,
                                                   const float* __restrict__ bias,
                                                   const float* __restrict__ R,
                                                   OutT* __restrict__ D,
                                                   int K, int N) {
    constexpr int LDK = 40;
    __shared__ bf16 As[BM * LDK];
    __shared__ bf16 Bs[BN * LDK];
    int tid = threadIdx.x;
    int wave = tid >> 6, lane = tid & 63;
    int l15 = lane & 15, quad = lane >> 4;
    constexpr int WCOLS = BN / WN;
    int wr = wave / WCOLS, wc = wave % WCOLS;
    int m0 = blockIdx.y * BM, n0 = blockIdx.x * BN;
    constexpr int MI = WM / 16, NJ = WN / 16;
    floatx4 acc[MI][NJ];
    #pragma unroll
    for (int i = 0; i < MI; ++i)
        #pragma unroll
        for (int j = 0; j < NJ; ++j)
            acc[i][j] = (floatx4){0.f, 0.f, 0.f, 0.f};

    for (int k0 = 0; k0 < K; k0 += 32) {
        #pragma unroll
        for (int c = tid; c < BM * 4; c += 256) {
            int row = c >> 2, off = (c & 3) * 8;
            *(uint4*)&As[row * LDK + off] =
                *(const uint4*)&A[(size_t)(m0 + row) * K + k0 + off];
        }
        #pragma unroll
        for (int c = tid; c < BN * 4; c += 256) {
            int row = c >> 2, off = (c & 3) * 8;
            *(uint4*)&Bs[row * LDK + off] =
                *(const uint4*)&Bt[(size_t)(n0 + row) * K + k0 + off];
        }
        __syncthreads();
        short8 af[MI], bfr[NJ];
        #pragma unroll
        for (int i = 0; i < MI; ++i)
            af[i] = *(const short8*)&As[(wr * WM + i * 16 + l15) * LDK + quad * 8];
        #pragma unroll
        for (int j = 0; j < NJ; ++j)
            bfr[j] = *(const short8*)&Bs[(wc * WN + j * 16 + l15) * LDK + quad * 8];
        #pragma unroll
        for (int i = 0; i < MI; ++i)
            #pragma unroll
            for (int j = 0; j < NJ; ++j)
                acc[i][j] = __builtin_amdgcn_mfma_f32_16x16x32_bf16(af[i], bfr[j], acc[i][j], 0, 0, 0);
        __syncthreads();
    }
    #pragma unroll
    for (int i = 0; i < MI; ++i) {
        #pragma unroll
        for (int j = 0; j < NJ; ++j) {
            int nn = n0 + wc * WN + j * 16 + l15;
            float bv = bias[nn];
            #pragma unroll
            for (int rg = 0; rg < 4; ++rg) {
                int m = m0 + wr * WM + i * 16 + quad * 4 + rg;
                float v = acc[i][j][rg] + bv;
                if (R) v += R[(size_t)m * N + nn];
                if constexpr (sizeof(OutT) == 2)
                    D[(size_t)m * N + nn] = __float2bfloat16(v);
                else
                    D[(size_t)m * N + nn] = v;
            }
        }
    }
}

// ---- row-tiled 7x7 neighborhood attention; per-(xq,ky) logits, q in registers.
__global__ __launch_bounds__(256) void k_attn(const bf16* __restrict__ qkv,
                                              const float* __restrict__ rpb,
                                              bf16* __restrict__ out) {
    int blk = blockIdx.x;            // ((n*40 + y)*4 + head)
    int head = blk & 3;
    int ny = blk >> 2;
    int n = ny / 40, y = ny % 40;
    int sy = min(max(y - 3, 0), HH - 7);
    __shared__ bf16 qsb[40][40];     // unscaled q, bf16
    __shared__ bf16 KVs[7 * KVP];    // K then V, plane stride 1608
    __shared__ float lg[40][49];
    int tid = threadIdx.x;
    if (tid < 160) {
        int xq = tid >> 2, d8 = (tid & 3) * 8;
        *(uint4*)&qsb[xq][d8] =
            *(const uint4*)(qkv + ((size_t)(n * 1600 + y * 40 + xq)) * 384 + head * 32 + d8);
    }
    for (int i2 = tid; i2 < 1120; i2 += 256) {     // K window
        int d8 = i2 & 3, kx = (i2 >> 2) % 40, ky = i2 / 160;
        size_t base = ((size_t)(n * 1600 + (sy + ky) * 40 + kx)) * 384 + 128 + head * 32 + d8 * 8;
        *(uint4*)&KVs[ky * KVP + kx * 40 + d8 * 8] = *(const uint4*)(qkv + base);
    }
    __syncthreads();
    for (int p2 = tid; p2 < 280; p2 += 256) {      // logits: thread per (xq, ky)
        int xq = p2 / 7, ky = p2 - (p2 / 7) * 7;
        int sx = min(max(xq - 3, 0), WW - 7);
        float qf[32];
        const __hip_bfloat162* qp = (const __hip_bfloat162*)&qsb[xq][0];
        #pragma unroll
        for (int c = 0; c < 16; ++c) {
            float2 f = __bfloat1622float2(qp[c]);
            qf[2 * c] = f.x; qf[2 * c + 1] = f.y;
        }
        const float* rb = rpb + head * 169 + (sy + ky - y + 6) * 13 + (sx - xq + 6);
        int kbase = ky * KVP + sx * 40;
        #pragma unroll
        for (int jx = 0; jx < 7; ++jx) {
            const __hip_bfloat162* kp = (const __hip_bfloat162*)&KVs[kbase + jx * 40];
            float dot = 0.f;
            #pragma unroll
            for (int c = 0; c < 16; ++c) {
                float2 kv = __bfloat1622float2(kp[c]);
                dot += qf[2 * c] * kv.x + qf[2 * c + 1] * kv.y;
            }
            lg[xq][ky * 7 + jx] = dot * 0.1767766952966369f + rb[jx];
        }
    }
    __syncthreads();
    for (int i2 = tid; i2 < 1120; i2 += 256) {     // V window (overwrite K)
        int d8 = i2 & 3, kx = (i2 >> 2) % 40, ky = i2 / 160;
        size_t base = ((size_t)(n * 1600 + (sy + ky) * 40 + kx)) * 384 + 256 + head * 32 + d8 * 8;
        *(uint4*)&KVs[ky * KVP + kx * 40 + d8 * 8] = *(const uint4*)(qkv + base);
    }
    if (tid < 40) {
        float m = -1e30f;
        for (int j = 0; j < 49; ++j) m = fmaxf(m, lg[tid][j]);
        float s = 0.f;
        for (int j = 0; j < 49; ++j) { float e = expf(lg[tid][j] - m); lg[tid][j] = e; s += e; }
        float inv = 1.0f / s;
        for (int j = 0; j < 49; ++j) lg[tid][j] *= inv;
    }
    __syncthreads();
    for (int o = tid; o < 640; o += 256) {         // PV reduce
        int xq = o >> 4, dp = (o & 15) * 2;
        int sx = min(max(xq - 3, 0), WW - 7);
        float a0 = 0.f, a1 = 0.f;
        #pragma unroll
        for (int ky = 0; ky < 7; ++ky) {
            int vbase = ky * KVP + sx * 40 + dp;
            #pragma unroll
            for (int jx = 0; jx < 7; ++jx) {
                float p = lg[xq][ky * 7 + jx];
                float2 v = __bfloat1622float2(*(const __hip_bfloat162*)&KVs[vbase + jx * 40]);
                a0 += p * v.x; a1 += p * v.y;
            }
        }
        __hip_bfloat162 o2;
        o2.x = __float2bfloat16(a0); o2.y = __float2bfloat16(a1);
        *(__hip_bfloat162*)(out + ((size_t)(n * 1600 + y * 40 + xq)) * 128 + head * 32 + dp) = o2;
    }
}

// ---- depthwise 3x3x3 conv + bias + exact GELU; fp32 in, bf16 out.
// 512 scalar-channel threads, x split in halves: 1280 blocks. (measured-best shape)
__global__ __launch_bounds__(512) void k_dwconv(const float* __restrict__ inp,   // [16][1600][512] f32
                                                const float* __restrict__ w,
                                                const float* __restrict__ bias,
                                                bf16* __restrict__ outp) {
    int blk = blockIdx.x;            // (n*40 + y)*2 + xh
    int xh = blk & 1;
    int ny = blk >> 1;
    int n = ny / 40, y = ny - n * 40;
    int b = n >> 3, t = n & 7;
    int m = threadIdx.x;
    float wr[27];
    #pragma unroll
    for (int i = 0; i < 27; ++i) wr[i] = w[i * 512 + m];
    float bs = bias[m];
    const float* rp[9];
    #pragma unroll
    for (int dt = 0; dt < 3; ++dt)
        #pragma unroll
        for (int dy = 0; dy < 3; ++dy) {
            int tt = t + dt - 1, yy = y + dy - 1;
            bool v = (tt >= 0 && tt < 8 && yy >= 0 && yy < 40);
            rp[dt * 3 + dy] = v ? inp + ((size_t)((b * 8 + tt) * 1600 + yy * 40)) * 512 + m
                                : nullptr;
        }
    int x0 = xh * 20;
    float c0[9], c1[9], c2[9];
    #pragma unroll
    for (int p = 0; p < 9; ++p) {
        c0[p] = (x0 > 0 && rp[p]) ? rp[p][(size_t)(x0 - 1) * 512] : 0.f;
        c1[p] = rp[p] ? rp[p][(size_t)x0 * 512] : 0.f;
    }
    size_t outbase = ((size_t)(n * 1600 + y * 40)) * 512 + m;
    for (int x = x0; x < x0 + 20; ++x) {
        #pragma unroll
        for (int p = 0; p < 9; ++p)
            c2[p] = (x < 39 && rp[p]) ? rp[p][(size_t)(x + 1) * 512] : 0.f;
        float acc = bs;
        #pragma unroll
        for (int p = 0; p < 9; ++p)
            acc += wr[p * 3 + 0] * c0[p] + wr[p * 3 + 1] * c1[p] + wr[p * 3 + 2] * c2[p];
        float g = 0.5f * acc * (1.0f + erff(acc * 0.70710678118654752f));
        outp[outbase + (size_t)x * 512] = __float2bfloat16(g);
        #pragma unroll
        for (int p = 0; p < 9; ++p) { c0[p] = c1[p]; c1[p] = c2[p]; }
    }
}

// ---- final LN + transpose via LDS tile, coalesced stores.
__global__ __launch_bounds__(256) void k_ln_out(const float* __restrict__ src,
                                                const float* __restrict__ gamma,
                                                const float* __restrict__ beta,
                                                float* __restrict__ out) {
    int blk = blockIdx.x;
    int n = blk / 50, ri = blk % 50;
    int r0 = ri * 32;
    int b = n >> 3, t = n & 7;
    __shared__ float tile[128][33];
    int tid = threadIdx.x;
    int tok = tid >> 3, sub = tid & 7;
    const float* sp = src + ((size_t)(n * 1600 + r0 + tok)) * 128 + sub * 16;
    float v[16];
    float s = 0.f, q = 0.f;
    #pragma unroll
    for (int i = 0; i < 16; i += 4) {
        float4 f = *(const float4*)(sp + i);
        v[i] = f.x; v[i + 1] = f.y; v[i + 2] = f.z; v[i + 3] = f.w;
        s += f.x + f.y + f.z + f.w;
        q += f.x * f.x + f.y * f.y + f.z * f.z + f.w * f.w;
    }
    #pragma unroll
    for (int o = 4; o > 0; o >>= 1) { s += __shfl_xor(s, o); q += __shfl_xor(q, o); }
    float mean = s * (1.0f / 128.0f);
    float var = q * (1.0f / 128.0f) - mean * mean;
    float inv = rsqrtf(var + 1e-5f);
    #pragma unroll
    for (int i = 0; i < 16; ++i) {
        int ch = sub * 16 + i;
        tile[ch][tok] = (v[i] - mean) * inv * gamma[ch] + beta[ch];
    }
    __syncthreads();
    #pragma unroll
    for (int it = 0; it < 16; ++it) {
        int idx = it * 256 + tid;
        int ch = idx >> 5, tk = idx & 31;
        out[((size_t)((b * 128 + ch) * 8 + t)) * 1600 + r0 + tk] = tile[ch][tk];
    }
}

extern "C" void kernel_launch(void* const* d_in, const int* in_sizes, int n_in,
                              void* d_out, int out_size, void* d_ws, size_t ws_size,
                              hipStream_t stream) {
    const float* x      = (const float*)d_in[0];
    const float* ln1_g  = (const float*)d_in[1];
    const float* ln1_b  = (const float*)d_in[2];
    const float* qkv_w  = (const float*)d_in[3];
    const float* qkv_b  = (const float*)d_in[4];
    const float* rpb    = (const float*)d_in[5];
    const float* proj_w = (const float*)d_in[6];
    const float* proj_b = (const float*)d_in[7];
    const float* ln2_g  = (const float*)d_in[8];
    const float* ln2_b  = (const float*)d_in[9];
    const float* fc1_w  = (const float*)d_in[10];
    const float* fc1_b  = (const float*)d_in[11];
    const float* dw_w   = (const float*)d_in[12];
    const float* dw_b   = (const float*)d_in[13];
    const float* fc2_w  = (const float*)d_in[14];
    const float* fc2_b  = (const float*)d_in[15];
    const float* out_g  = (const float*)d_in[16];
    const float* out_b  = (const float*)d_in[17];
    float* out = (float*)d_out;

    // workspace: h f32 | f1 f32 | qkvb bf16 | f2b bf16 | abuf bf16 | wt bf16
    float* h    = (float*)d_ws;
    float* f1   = h + (size_t)NTOK * 128;
    bf16* qkvb  = (bf16*)(f1 + (size_t)NTOK * 512);
    bf16* f2b   = qkvb + (size_t)NTOK * 384;
    bf16* abuf  = f2b  + (size_t)NTOK * 512;
    bf16* wt    = abuf + (size_t)NTOK * 128;

    k_wt<<<96, 256, 0, stream>>>(qkv_w, proj_w, fc1_w, fc2_w, wt);
    k_transpose_in<<<NIMG * 200, 256, 0, stream>>>(x, h);
    for (int l = 0; l < 2; ++l) {
        const bf16* wtl = wt + (size_t)l * WT_L;
        k_lngemm<bf16><<<dim3(3, 200), 256, 0, stream>>>(
            h, wtl + WT_QKV, ln1_g + l * 128, ln1_b + l * 128, qkv_b + l * 384, qkvb, 384);
        k_attn<<<NIMG * HH * NHEAD, 256, 0, stream>>>(qkvb, rpb + l * 4 * 169, abuf);
        k_gemm_mfma<64, 128, 32, 64, float><<<dim3(1, 400), 256, 0, stream>>>(
            abuf, wtl + WT_PROJ, proj_b + l * 128, h, h, 128, 128);
        k_lngemm<float><<<dim3(4, 200), 256, 0, stream>>>(
            h, wtl + WT_FC1, ln2_g + l * 128, ln2_b + l * 128, fc1_b + l * 512, f1, 512);
        k_dwconv<<<NIMG * HH * 2, 512, 0, stream>>>(f1, dw_w + l * 27 * 512, dw_b + l * 512, f2b);
        k_gemm_mfma<64, 128, 32, 64, float><<<dim3(1, 400), 256, 0, stream>>>(
            f2b, wtl + WT_FC2, fc2_b + l * 128, h, h, 512, 128);
    }
    k_ln_out<<<NIMG * 50, 256, 0, stream>>>(h, out_g, out_b, out);
}

// Round 10
// 440.246 us; speedup vs baseline: 1.3065x; 1.0395x over previous
//
#include <hip/hip_runtime.h>
#include <hip/hip_bf16.h>
#include <math.h>

typedef __hip_bfloat16 bf16;
typedef __attribute__((ext_vector_type(8))) short short8;
typedef __attribute__((ext_vector_type(4))) float floatx4;

#define HH 40
#define WW 40
#define CC 128
#define TT 8
#define NIMG 16           // B*T
#define NTOK 25600        // NIMG*HH*WW
#define MDIM 512
#define NHEAD 4
#define KVP 1608          // K/V LDS plane stride in bf16 (40*40 + 8)

// weight-transpose buffer offsets (bf16 elems), per layer
#define WT_QKV 0
#define WT_PROJ 49152
#define WT_FC1  65536
#define WT_FC2  131072
#define WT_L    196608

// ---- input transpose via LDS tiles: x (b,c,t,y,x) -> h (n,y,x,c), both coalesced.
__global__ __launch_bounds__(256) void k_transpose_in(const float* __restrict__ x,
                                                      float* __restrict__ h) {
    int blk = blockIdx.x;
    int n = blk / 200; int r = blk % 200; int ci = r / 50, ri = r % 50;
    int b = n >> 3, t = n & 7;
    int c0 = ci * 32, r0 = ri * 32;
    __shared__ float tile[32][33];
    int tid = threadIdx.x;
    int lc = tid >> 5, lr = tid & 31;         // 8 x 32
    #pragma unroll
    for (int it = 0; it < 4; ++it) {
        int cc = it * 8 + lc;
        tile[cc][lr] = x[((size_t)((b * 128 + c0 + cc) * 8 + t)) * 1600 + r0 + lr];
    }
    __syncthreads();
    #pragma unroll
    for (int it = 0; it < 4; ++it) {
        int rr = it * 8 + lc;
        h[((size_t)(n * 1600 + r0 + rr)) * 128 + c0 + lr] = tile[lr][rr];
    }
}

// ---- weight convert+transpose: W[K,N] fp32 -> Wt[N,K] bf16, 64x64 LDS tiles.
__global__ __launch_bounds__(256) void k_wt(const float* __restrict__ qkv_w,
                                            const float* __restrict__ proj_w,
                                            const float* __restrict__ fc1_w,
                                            const float* __restrict__ fc2_w,
                                            bf16* __restrict__ wt) {
    __shared__ float tile[64][65];
    int id = blockIdx.x;
    int l = id / 48, r = id % 48;
    const float* src; bf16* dst; int K_, N_, t;
    if (r < 12)      { src = qkv_w  + l * 128 * 384; dst = wt + l * WT_L + WT_QKV; K_ = 128; N_ = 384; t = r; }
    else if (r < 16) { src = proj_w + l * 128 * 128; dst = wt + l * WT_L + WT_PROJ; K_ = 128; N_ = 128; t = r - 12; }
    else if (r < 32) { src = fc1_w  + l * 128 * 512; dst = wt + l * WT_L + WT_FC1; K_ = 128; N_ = 512; t = r - 16; }
    else             { src = fc2_w  + l * 512 * 128; dst = wt + l * WT_L + WT_FC2; K_ = 512; N_ = 128; t = r - 32; }
    int KT = K_ >> 6;
    int k0 = (t % KT) * 64, n0 = (t / KT) * 64;
    int tid = threadIdx.x;
    for (int c = tid; c < 4096; c += 256) {
        int kk = c >> 6, nn = c & 63;
        tile[kk][nn] = src[(size_t)(k0 + kk) * N_ + n0 + nn];
    }
    __syncthreads();
    for (int c = tid; c < 4096; c += 256) {
        int nn = c >> 6, kk = c & 63;
        dst[(size_t)(n0 + nn) * K_ + k0 + kk] = __float2bfloat16(tile[kk][nn]);
    }
}

// ---- fused LayerNorm + MFMA GEMM: D = LN(A) @ Bt^T + bias. K=128, BM=64, BN=128.
// 4 waves 2x2 (WM=32, WN=64).
template<typename OutT>
__global__ __launch_bounds__(256) void k_lngemm(const float* __restrict__ A,   // [M][128] fp32
                                                const bf16* __restrict__ Bt,   // [N][128] bf16
                                                const float* __restrict__ g,
                                                const float* __restrict__ be,
                                                const float* __restrict__ bias,
                                                OutT* __restrict__ D,
                                                int N) {
    constexpr int LDK = 40;
    __shared__ bf16 As[64 * LDK];
    __shared__ bf16 Bs[128 * LDK];
    __shared__ float sMean[64], sRstd[64], sG[128], sB[128];
    int tid = threadIdx.x;
    int m0 = blockIdx.y * 64, n0 = blockIdx.x * 128;
    // row stats: 4 threads per row (32 channels each)
    {
        int row = tid >> 2, q4 = tid & 3;
        const float* p = A + (size_t)(m0 + row) * 128 + q4 * 32;
        float s = 0.f, q = 0.f;
        #pragma unroll
        for (int i = 0; i < 32; i += 4) {
            float4 f = *(const float4*)(p + i);
            s += f.x + f.y + f.z + f.w;
            q += f.x * f.x + f.y * f.y + f.z * f.z + f.w * f.w;
        }
        s += __shfl_xor(s, 1); q += __shfl_xor(q, 1);
        s += __shfl_xor(s, 2); q += __shfl_xor(q, 2);
        if (q4 == 0) {
            float mean = s * (1.0f / 128.0f);
            float var = q * (1.0f / 128.0f) - mean * mean;
            sMean[row] = mean;
            sRstd[row] = rsqrtf(var + 1e-5f);
        }
        if (tid < 128) { sG[tid] = g[tid]; sB[tid] = be[tid]; }
    }
    __syncthreads();
    int wave = tid >> 6, lane = tid & 63;
    int l15 = lane & 15, quad = lane >> 4;
    int wr = wave >> 1, wc = wave & 1;
    floatx4 acc[2][4];
    #pragma unroll
    for (int i = 0; i < 2; ++i)
        #pragma unroll
        for (int j = 0; j < 4; ++j)
            acc[i][j] = (floatx4){0.f, 0.f, 0.f, 0.f};

    for (int k0 = 0; k0 < 128; k0 += 32) {
        // A: normalize while staging, 64 rows x 32 k = 512 float4
        #pragma unroll
        for (int it = 0; it < 2; ++it) {
            int c = tid + it * 256;
            int row = c >> 3, kq = (c & 7) * 4;
            float4 f = *(const float4*)(A + (size_t)(m0 + row) * 128 + k0 + kq);
            float mean = sMean[row], rst = sRstd[row];
            float r0v = (f.x - mean) * rst * sG[k0 + kq]     + sB[k0 + kq];
            float r1v = (f.y - mean) * rst * sG[k0 + kq + 1] + sB[k0 + kq + 1];
            float r2v = (f.z - mean) * rst * sG[k0 + kq + 2] + sB[k0 + kq + 2];
            float r3v = (f.w - mean) * rst * sG[k0 + kq + 3] + sB[k0 + kq + 3];
            __hip_bfloat162 p0, p1;
            p0.x = __float2bfloat16(r0v); p0.y = __float2bfloat16(r1v);
            p1.x = __float2bfloat16(r2v); p1.y = __float2bfloat16(r3v);
            *(__hip_bfloat162*)&As[row * LDK + kq]     = p0;
            *(__hip_bfloat162*)&As[row * LDK + kq + 2] = p1;
        }
        // B staging: 128 rows x 4 uint4
        #pragma unroll
        for (int c = tid; c < 512; c += 256) {
            int row = c >> 2, off = (c & 3) * 8;
            *(uint4*)&Bs[row * LDK + off] =
                *(const uint4*)&Bt[(size_t)(n0 + row) * 128 + k0 + off];
        }
        __syncthreads();
        short8 af[2], bfr[4];
        #pragma unroll
        for (int i = 0; i < 2; ++i)
            af[i] = *(const short8*)&As[(wr * 32 + i * 16 + l15) * LDK + quad * 8];
        #pragma unroll
        for (int j = 0; j < 4; ++j)
            bfr[j] = *(const short8*)&Bs[(wc * 64 + j * 16 + l15) * LDK + quad * 8];
        #pragma unroll
        for (int i = 0; i < 2; ++i)
            #pragma unroll
            for (int j = 0; j < 4; ++j)
                acc[i][j] = __builtin_amdgcn_mfma_f32_16x16x32_bf16(af[i], bfr[j], acc[i][j], 0, 0, 0);
        __syncthreads();
    }
    #pragma unroll
    for (int i = 0; i < 2; ++i) {
        #pragma unroll
        for (int j = 0; j < 4; ++j) {
            int nn = n0 + wc * 64 + j * 16 + l15;
            float bv = bias[nn];
            #pragma unroll
            for (int rg = 0; rg < 4; ++rg) {
                int m = m0 + wr * 32 + i * 16 + quad * 4 + rg;
                float v = acc[i][j][rg] + bv;
                if constexpr (sizeof(OutT) == 2)
                    D[(size_t)m * N + nn] = __float2bfloat16(v);
                else
                    D[(size_t)m * N + nn] = v;
            }
        }
    }
}

// ---- MFMA bf16 GEMM: D[M,N] = A[M,K] @ Bt[N,K]^T + bias (+R).
template<int BM, int BN, int WM, int WN, typename OutT>
__global__ __launch_bounds__(256) void k_gemm_mfma(const bf16* __restrict__ A,
                                                   const bf16* __restrict__ Bt,
                                                   const float* __restrict__ bias,
                                                   const float* __restrict__ R,
                                                   OutT* __restrict__ D,
                                                   int K, int N) {
    constexpr int LDK = 40;
    __shared__ bf16 As[BM * LDK];
    __shared__ bf16 Bs[BN * LDK];
    int tid = threadIdx.x;
    int wave = tid >> 6, lane = tid & 63;
    int l15 = lane & 15, quad = lane >> 4;
    constexpr int WCOLS = BN / WN;
    int wr = wave / WCOLS, wc = wave % WCOLS;
    int m0 = blockIdx.y * BM, n0 = blockIdx.x * BN;
    constexpr int MI = WM / 16, NJ = WN / 16;
    floatx4 acc[MI][NJ];
    #pragma unroll
    for (int i = 0; i < MI; ++i)
        #pragma unroll
        for (int j = 0; j < NJ; ++j)
            acc[i][j] = (floatx4){0.f, 0.f, 0.f, 0.f};

    for (int k0 = 0; k0 < K; k0 += 32) {
        #pragma unroll
        for (int c = tid; c < BM * 4; c += 256) {
            int row = c >> 2, off = (c & 3) * 8;
            *(uint4*)&As[row * LDK + off] =
                *(const uint4*)&A[(size_t)(m0 + row) * K + k0 + off];
        }
        #pragma unroll
        for (int c = tid; c < BN * 4; c += 256) {
            int row = c >> 2, off = (c & 3) * 8;
            *(uint4*)&Bs[row * LDK + off] =
                *(const uint4*)&Bt[(size_t)(n0 + row) * K + k0 + off];
        }
        __syncthreads();
        short8 af[MI], bfr[NJ];
        #pragma unroll
        for (int i = 0; i < MI; ++i)
            af[i] = *(const short8*)&As[(wr * WM + i * 16 + l15) * LDK + quad * 8];
        #pragma unroll
        for (int j = 0; j < NJ; ++j)
            bfr[j] = *(const short8*)&Bs[(wc * WN + j * 16 + l15) * LDK + quad * 8];
        #pragma unroll
        for (int i = 0; i < MI; ++i)
            #pragma unroll
            for (int j = 0; j < NJ; ++j)
                acc[i][j] = __builtin_amdgcn_mfma_f32_16x16x32_bf16(af[i], bfr[j], acc[i][j], 0, 0, 0);
        __syncthreads();
    }
    #pragma unroll
    for (int i = 0; i < MI; ++i) {
        #pragma unroll
        for (int j = 0; j < NJ; ++j) {
            int nn = n0 + wc * WN + j * 16 + l15;
            float bv = bias[nn];
            #pragma unroll
            for (int rg = 0; rg < 4; ++rg) {
                int m = m0 + wr * WM + i * 16 + quad * 4 + rg;
                float v = acc[i][j][rg] + bv;
                if (R) v += R[(size_t)m * N + nn];
                if constexpr (sizeof(OutT) == 2)
                    D[(size_t)m * N + nn] = __float2bfloat16(v);
                else
                    D[(size_t)m * N + nn] = v;
            }
        }
    }
}

// ---- row-tiled 7x7 neighborhood attention; per-(xq,ky) logits, q in registers.
__global__ __launch_bounds__(256) void k_attn(const bf16* __restrict__ qkv,
                                              const float* __restrict__ rpb,
                                              bf16* __restrict__ out) {
    int blk = blockIdx.x;            // ((n*40 + y)*4 + head)
    int head = blk & 3;
    int ny = blk >> 2;
    int n = ny / 40, y = ny % 40;
    int sy = min(max(y - 3, 0), HH - 7);
    __shared__ bf16 qsb[40][40];     // unscaled q, bf16
    __shared__ bf16 KVs[7 * KVP];    // K then V, plane stride 1608
    __shared__ float lg[40][49];
    int tid = threadIdx.x;
    if (tid < 160) {
        int xq = tid >> 2, d8 = (tid & 3) * 8;
        *(uint4*)&qsb[xq][d8] =
            *(const uint4*)(qkv + ((size_t)(n * 1600 + y * 40 + xq)) * 384 + head * 32 + d8);
    }
    for (int i2 = tid; i2 < 1120; i2 += 256) {     // K window
        int d8 = i2 & 3, kx = (i2 >> 2) % 40, ky = i2 / 160;
        size_t base = ((size_t)(n * 1600 + (sy + ky) * 40 + kx)) * 384 + 128 + head * 32 + d8 * 8;
        *(uint4*)&KVs[ky * KVP + kx * 40 + d8 * 8] = *(const uint4*)(qkv + base);
    }
    __syncthreads();
    for (int p2 = tid; p2 < 280; p2 += 256) {      // logits: thread per (xq, ky)
        int xq = p2 / 7, ky = p2 - (p2 / 7) * 7;
        int sx = min(max(xq - 3, 0), WW - 7);
        float qf[32];
        const __hip_bfloat162* qp = (const __hip_bfloat162*)&qsb[xq][0];
        #pragma unroll
        for (int c = 0; c < 16; ++c) {
            float2 f = __bfloat1622float2(qp[c]);
            qf[2 * c] = f.x; qf[2 * c + 1] = f.y;
        }
        const float* rb = rpb + head * 169 + (sy + ky - y + 6) * 13 + (sx - xq + 6);
        int kbase = ky * KVP + sx * 40;
        #pragma unroll
        for (int jx = 0; jx < 7; ++jx) {
            const __hip_bfloat162* kp = (const __hip_bfloat162*)&KVs[kbase + jx * 40];
            float dot = 0.f;
            #pragma unroll
            for (int c = 0; c < 16; ++c) {
                float2 kv = __bfloat1622float2(kp[c]);
                dot += qf[2 * c] * kv.x + qf[2 * c + 1] * kv.y;
            }
            lg[xq][ky * 7 + jx] = dot * 0.1767766952966369f + rb[jx];
        }
    }
    __syncthreads();
    for (int i2 = tid; i2 < 1120; i2 += 256) {     // V window (overwrite K)
        int d8 = i2 & 3, kx = (i2 >> 2) % 40, ky = i2 / 160;
        size_t base = ((size_t)(n * 1600 + (sy + ky) * 40 + kx)) * 384 + 256 + head * 32 + d8 * 8;
        *(uint4*)&KVs[ky * KVP + kx * 40 + d8 * 8] = *(const uint4*)(qkv + base);
    }
    if (tid < 40) {
        float m = -1e30f;
        for (int j = 0; j < 49; ++j) m = fmaxf(m, lg[tid][j]);
        float s = 0.f;
        for (int j = 0; j < 49; ++j) { float e = expf(lg[tid][j] - m); lg[tid][j] = e; s += e; }
        float inv = 1.0f / s;
        for (int j = 0; j < 49; ++j) lg[tid][j] *= inv;
    }
    __syncthreads();
    for (int o = tid; o < 640; o += 256) {         // PV reduce
        int xq = o >> 4, dp = (o & 15) * 2;
        int sx = min(max(xq - 3, 0), WW - 7);
        float a0 = 0.f, a1 = 0.f;
        #pragma unroll
        for (int ky = 0; ky < 7; ++ky) {
            int vbase = ky * KVP + sx * 40 + dp;
            #pragma unroll
            for (int jx = 0; jx < 7; ++jx) {
                float p = lg[xq][ky * 7 + jx];
                float2 v = __bfloat1622float2(*(const __hip_bfloat162*)&KVs[vbase + jx * 40]);
                a0 += p * v.x; a1 += p * v.y;
            }
        }
        __hip_bfloat162 o2;
        o2.x = __float2bfloat16(a0); o2.y = __float2bfloat16(a1);
        *(__hip_bfloat162*)(out + ((size_t)(n * 1600 + y * 40 + xq)) * 128 + head * 32 + dp) = o2;
    }
}

// ---- depthwise 3x3x3 conv + bias + exact GELU; fp32 in, bf16 out.
// 512 scalar-channel threads, x split in halves: 1280 blocks. (measured-best shape)
__global__ __launch_bounds__(512) void k_dwconv(const float* __restrict__ inp,   // [16][1600][512] f32
                                                const float* __restrict__ w,
                                                const float* __restrict__ bias,
                                                bf16* __restrict__ outp) {
    int blk = blockIdx.x;            // (n*40 + y)*2 + xh
    int xh = blk & 1;
    int ny = blk >> 1;
    int n = ny / 40, y = ny - n * 40;
    int b = n >> 3, t = n & 7;
    int m = threadIdx.x;
    float wr[27];
    #pragma unroll
    for (int i = 0; i < 27; ++i) wr[i] = w[i * 512 + m];
    float bs = bias[m];
    const float* rp[9];
    #pragma unroll
    for (int dt = 0; dt < 3; ++dt)
        #pragma unroll
        for (int dy = 0; dy < 3; ++dy) {
            int tt = t + dt - 1, yy = y + dy - 1;
            bool v = (tt >= 0 && tt < 8 && yy >= 0 && yy < 40);
            rp[dt * 3 + dy] = v ? inp + ((size_t)((b * 8 + tt) * 1600 + yy * 40)) * 512 + m
                                : nullptr;
        }
    int x0 = xh * 20;
    float c0[9], c1[9], c2[9];
    #pragma unroll
    for (int p = 0; p < 9; ++p) {
        c0[p] = (x0 > 0 && rp[p]) ? rp[p][(size_t)(x0 - 1) * 512] : 0.f;
        c1[p] = rp[p] ? rp[p][(size_t)x0 * 512] : 0.f;
    }
    size_t outbase = ((size_t)(n * 1600 + y * 40)) * 512 + m;
    for (int x = x0; x < x0 + 20; ++x) {
        #pragma unroll
        for (int p = 0; p < 9; ++p)
            c2[p] = (x < 39 && rp[p]) ? rp[p][(size_t)(x + 1) * 512] : 0.f;
        float acc = bs;
        #pragma unroll
        for (int p = 0; p < 9; ++p)
            acc += wr[p * 3 + 0] * c0[p] + wr[p * 3 + 1] * c1[p] + wr[p * 3 + 2] * c2[p];
        float g = 0.5f * acc * (1.0f + erff(acc * 0.70710678118654752f));
        outp[outbase + (size_t)x * 512] = __float2bfloat16(g);
        #pragma unroll
        for (int p = 0; p < 9; ++p) { c0[p] = c1[p]; c1[p] = c2[p]; }
    }
}

// ---- final LN + transpose via LDS tile, coalesced stores.
__global__ __launch_bounds__(256) void k_ln_out(const float* __restrict__ src,
                                                const float* __restrict__ gamma,
                                                const float* __restrict__ beta,
                                                float* __restrict__ out) {
    int blk = blockIdx.x;
    int n = blk / 50, ri = blk % 50;
    int r0 = ri * 32;
    int b = n >> 3, t = n & 7;
    __shared__ float tile[128][33];
    int tid = threadIdx.x;
    int tok = tid >> 3, sub = tid & 7;
    const float* sp = src + ((size_t)(n * 1600 + r0 + tok)) * 128 + sub * 16;
    float v[16];
    float s = 0.f, q = 0.f;
    #pragma unroll
    for (int i = 0; i < 16; i += 4) {
        float4 f = *(const float4*)(sp + i);
        v[i] = f.x; v[i + 1] = f.y; v[i + 2] = f.z; v[i + 3] = f.w;
        s += f.x + f.y + f.z + f.w;
        q += f.x * f.x + f.y * f.y + f.z * f.z + f.w * f.w;
    }
    #pragma unroll
    for (int o = 4; o > 0; o >>= 1) { s += __shfl_xor(s, o); q += __shfl_xor(q, o); }
    float mean = s * (1.0f / 128.0f);
    float var = q * (1.0f / 128.0f) - mean * mean;
    float inv = rsqrtf(var + 1e-5f);
    #pragma unroll
    for (int i = 0; i < 16; ++i) {
        int ch = sub * 16 + i;
        tile[ch][tok] = (v[i] - mean) * inv * gamma[ch] + beta[ch];
    }
    __syncthreads();
    #pragma unroll
    for (int it = 0; it < 16; ++it) {
        int idx = it * 256 + tid;
        int ch = idx >> 5, tk = idx & 31;
        out[((size_t)((b * 128 + ch) * 8 + t)) * 1600 + r0 + tk] = tile[ch][tk];
    }
}

extern "C" void kernel_launch(void* const* d_in, const int* in_sizes, int n_in,
                              void* d_out, int out_size, void* d_ws, size_t ws_size,
                              hipStream_t stream) {
    const float* x      = (const float*)d_in[0];
    const float* ln1_g  = (const float*)d_in[1];
    const float* ln1_b  = (const float*)d_in[2];
    const float* qkv_w  = (const float*)d_in[3];
    const float* qkv_b  = (const float*)d_in[4];
    const float* rpb    = (const float*)d_in[5];
    const float* proj_w = (const float*)d_in[6];
    const float* proj_b = (const float*)d_in[7];
    const float* ln2_g  = (const float*)d_in[8];
    const float* ln2_b  = (const float*)d_in[9];
    const float* fc1_w  = (const float*)d_in[10];
    const float* fc1_b  = (const float*)d_in[11];
    const float* dw_w   = (const float*)d_in[12];
    const float* dw_b   = (const float*)d_in[13];
    const float* fc2_w  = (const float*)d_in[14];
    const float* fc2_b  = (const float*)d_in[15];
    const float* out_g  = (const float*)d_in[16];
    const float* out_b  = (const float*)d_in[17];
    float* out = (float*)d_out;

    // workspace: h f32 | f1 f32 | qkvb bf16 | f2b bf16 | abuf bf16 | wt bf16
    float* h    = (float*)d_ws;
    float* f1   = h + (size_t)NTOK * 128;
    bf16* qkvb  = (bf16*)(f1 + (size_t)NTOK * 512);
    bf16* f2b   = qkvb + (size_t)NTOK * 384;
    bf16* abuf  = f2b  + (size_t)NTOK * 512;
    bf16* wt    = abuf + (size_t)NTOK * 128;

    k_wt<<<96, 256, 0, stream>>>(qkv_w, proj_w, fc1_w, fc2_w, wt);
    k_transpose_in<<<NIMG * 200, 256, 0, stream>>>(x, h);
    for (int l = 0; l < 2; ++l) {
        const bf16* wtl = wt + (size_t)l * WT_L;
        k_lngemm<bf16><<<dim3(3, 400), 256, 0, stream>>>(
            h, wtl + WT_QKV, ln1_g + l * 128, ln1_b + l * 128, qkv_b + l * 384, qkvb, 384);
        k_attn<<<NIMG * HH * NHEAD, 256, 0, stream>>>(qkvb, rpb + l * 4 * 169, abuf);
        k_gemm_mfma<32, 128, 16, 64, float><<<dim3(1, 800), 256, 0, stream>>>(
            abuf, wtl + WT_PROJ, proj_b + l * 128, h, h, 128, 128);
        k_lngemm<float><<<dim3(4, 400), 256, 0, stream>>>(
            h, wtl + WT_FC1, ln2_g + l * 128, ln2_b + l * 128, fc1_b + l * 512, f1, 512);
        k_dwconv<<<NIMG * HH * 2, 512, 0, stream>>>(f1, dw_w + l * 27 * 512, dw_b + l * 512, f2b);
        k_gemm_mfma<32, 128, 16, 64, float><<<dim3(1, 800), 256, 0, stream>>>(
            f2b, wtl + WT_FC2, fc2_b + l * 128, h, h, 512, 128);
    }
    k_ln_out<<<NIMG * 50, 256, 0, stream>>>(h, out_g, out_b, out);
}

// Round 11
// 427.654 us; speedup vs baseline: 1.3450x; 1.0294x over previous
//
#include <hip/hip_runtime.h>
#include <hip/hip_bf16.h>
#include <math.h>

typedef __hip_bfloat16 bf16;
typedef __attribute__((ext_vector_type(8))) short short8;
typedef __attribute__((ext_vector_type(4))) float floatx4;

#define HH 40
#define WW 40
#define CC 128
#define TT 8
#define NIMG 16           // B*T
#define NTOK 25600        // NIMG*HH*WW
#define MDIM 512
#define NHEAD 4
#define KVP 1608          // K/V LDS plane stride in bf16

// weight-transpose buffer offsets (bf16 elems), per layer
#define WT_QKV 0
#define WT_PROJ 49152
#define WT_FC1  65536
#define WT_FC2  131072
#define WT_L    196608

// ---- input transpose via LDS tiles: x (b,c,t,y,x) -> h (n,y,x,c), both coalesced.
__global__ __launch_bounds__(256) void k_transpose_in(const float* __restrict__ x,
                                                      float* __restrict__ h) {
    int blk = blockIdx.x;
    int n = blk / 200; int r = blk % 200; int ci = r / 50, ri = r % 50;
    int b = n >> 3, t = n & 7;
    int c0 = ci * 32, r0 = ri * 32;
    __shared__ float tile[32][33];
    int tid = threadIdx.x;
    int lc = tid >> 5, lr = tid & 31;         // 8 x 32
    #pragma unroll
    for (int it = 0; it < 4; ++it) {
        int cc = it * 8 + lc;
        tile[cc][lr] = x[((size_t)((b * 128 + c0 + cc) * 8 + t)) * 1600 + r0 + lr];
    }
    __syncthreads();
    #pragma unroll
    for (int it = 0; it < 4; ++it) {
        int rr = it * 8 + lc;
        h[((size_t)(n * 1600 + r0 + rr)) * 128 + c0 + lr] = tile[lr][rr];
    }
}

// ---- weight convert+transpose: W[K,N] fp32 -> Wt[N,K] bf16, 64x64 LDS tiles.
__global__ __launch_bounds__(256) void k_wt(const float* __restrict__ qkv_w,
                                            const float* __restrict__ proj_w,
                                            const float* __restrict__ fc1_w,
                                            const float* __restrict__ fc2_w,
                                            bf16* __restrict__ wt) {
    __shared__ float tile[64][65];
    int id = blockIdx.x;
    int l = id / 48, r = id % 48;
    const float* src; bf16* dst; int K_, N_, t;
    if (r < 12)      { src = qkv_w  + l * 128 * 384; dst = wt + l * WT_L + WT_QKV; K_ = 128; N_ = 384; t = r; }
    else if (r < 16) { src = proj_w + l * 128 * 128; dst = wt + l * WT_L + WT_PROJ; K_ = 128; N_ = 128; t = r - 12; }
    else if (r < 32) { src = fc1_w  + l * 128 * 512; dst = wt + l * WT_L + WT_FC1; K_ = 128; N_ = 512; t = r - 16; }
    else             { src = fc2_w  + l * 512 * 128; dst = wt + l * WT_L + WT_FC2; K_ = 512; N_ = 128; t = r - 32; }
    int KT = K_ >> 6;
    int k0 = (t % KT) * 64, n0 = (t / KT) * 64;
    int tid = threadIdx.x;
    for (int c = tid; c < 4096; c += 256) {
        int kk = c >> 6, nn = c & 63;
        tile[kk][nn] = src[(size_t)(k0 + kk) * N_ + n0 + nn];
    }
    __syncthreads();
    for (int c = tid; c < 4096; c += 256) {
        int nn = c >> 6, kk = c & 63;
        dst[(size_t)(n0 + nn) * K_ + k0 + kk] = __float2bfloat16(tile[kk][nn]);
    }
}

// ---- fused LayerNorm + MFMA GEMM: D = LN(A) @ Bt^T + bias. K=128, BM=64, BN=128.
// Used only for layer-0 qkv (input h is fp32).
template<typename OutT>
__global__ __launch_bounds__(256) void k_lngemm(const float* __restrict__ A,
                                                const bf16* __restrict__ Bt,
                                                const float* __restrict__ g,
                                                const float* __restrict__ be,
                                                const float* __restrict__ bias,
                                                OutT* __restrict__ D,
                                                int N) {
    constexpr int LDK = 40;
    __shared__ bf16 As[64 * LDK];
    __shared__ bf16 Bs[128 * LDK];
    __shared__ float sMean[64], sRstd[64], sG[128], sB[128];
    int tid = threadIdx.x;
    int m0 = blockIdx.y * 64, n0 = blockIdx.x * 128;
    {
        int row = tid >> 2, q4 = tid & 3;
        const float* p = A + (size_t)(m0 + row) * 128 + q4 * 32;
        float s = 0.f, q = 0.f;
        #pragma unroll
        for (int i = 0; i < 32; i += 4) {
            float4 f = *(const float4*)(p + i);
            s += f.x + f.y + f.z + f.w;
            q += f.x * f.x + f.y * f.y + f.z * f.z + f.w * f.w;
        }
        s += __shfl_xor(s, 1); q += __shfl_xor(q, 1);
        s += __shfl_xor(s, 2); q += __shfl_xor(q, 2);
        if (q4 == 0) {
            float mean = s * (1.0f / 128.0f);
            float var = q * (1.0f / 128.0f) - mean * mean;
            sMean[row] = mean;
            sRstd[row] = rsqrtf(var + 1e-5f);
        }
        if (tid < 128) { sG[tid] = g[tid]; sB[tid] = be[tid]; }
    }
    __syncthreads();
    int wave = tid >> 6, lane = tid & 63;
    int l15 = lane & 15, quad = lane >> 4;
    int wr = wave >> 1, wc = wave & 1;
    floatx4 acc[2][4];
    #pragma unroll
    for (int i = 0; i < 2; ++i)
        #pragma unroll
        for (int j = 0; j < 4; ++j)
            acc[i][j] = (floatx4){0.f, 0.f, 0.f, 0.f};

    for (int k0 = 0; k0 < 128; k0 += 32) {
        #pragma unroll
        for (int it = 0; it < 2; ++it) {
            int c = tid + it * 256;
            int row = c >> 3, kq = (c & 7) * 4;
            float4 f = *(const float4*)(A + (size_t)(m0 + row) * 128 + k0 + kq);
            float mean = sMean[row], rst = sRstd[row];
            float r0v = (f.x - mean) * rst * sG[k0 + kq]     + sB[k0 + kq];
            float r1v = (f.y - mean) * rst * sG[k0 + kq + 1] + sB[k0 + kq + 1];
            float r2v = (f.z - mean) * rst * sG[k0 + kq + 2] + sB[k0 + kq + 2];
            float r3v = (f.w - mean) * rst * sG[k0 + kq + 3] + sB[k0 + kq + 3];
            __hip_bfloat162 p0, p1;
            p0.x = __float2bfloat16(r0v); p0.y = __float2bfloat16(r1v);
            p1.x = __float2bfloat16(r2v); p1.y = __float2bfloat16(r3v);
            *(__hip_bfloat162*)&As[row * LDK + kq]     = p0;
            *(__hip_bfloat162*)&As[row * LDK + kq + 2] = p1;
        }
        #pragma unroll
        for (int c = tid; c < 512; c += 256) {
            int row = c >> 2, off = (c & 3) * 8;
            *(uint4*)&Bs[row * LDK + off] =
                *(const uint4*)&Bt[(size_t)(n0 + row) * 128 + k0 + off];
        }
        __syncthreads();
        short8 af[2], bfr[4];
        #pragma unroll
        for (int i = 0; i < 2; ++i)
            af[i] = *(const short8*)&As[(wr * 32 + i * 16 + l15) * LDK + quad * 8];
        #pragma unroll
        for (int j = 0; j < 4; ++j)
            bfr[j] = *(const short8*)&Bs[(wc * 64 + j * 16 + l15) * LDK + quad * 8];
        #pragma unroll
        for (int i = 0; i < 2; ++i)
            #pragma unroll
            for (int j = 0; j < 4; ++j)
                acc[i][j] = __builtin_amdgcn_mfma_f32_16x16x32_bf16(af[i], bfr[j], acc[i][j], 0, 0, 0);
        __syncthreads();
    }
    #pragma unroll
    for (int i = 0; i < 2; ++i) {
        #pragma unroll
        for (int j = 0; j < 4; ++j) {
            int nn = n0 + wc * 64 + j * 16 + l15;
            float bv = bias[nn];
            #pragma unroll
            for (int rg = 0; rg < 4; ++rg) {
                int m = m0 + wr * 32 + i * 16 + quad * 4 + rg;
                float v = acc[i][j][rg] + bv;
                if constexpr (sizeof(OutT) == 2)
                    D[(size_t)m * N + nn] = __float2bfloat16(v);
                else
                    D[(size_t)m * N + nn] = v;
            }
        }
    }
}

// ---- MFMA bf16 GEMM: D[M,N] = A[M,K] @ Bt[N,K]^T + bias (+R).
template<int BM, int BN, int WM, int WN, typename OutT>
__global__ __launch_bounds__(256) void k_gemm_mfma(const bf16* __restrict__ A,
                                                   const bf16* __restrict__ Bt,
                                                   const float* __restrict__ bias,
                                                   const float* __restrict__ R,
                                                   OutT* __restrict__ D,
                                                   int K, int N) {
    constexpr int LDK = 40;
    __shared__ bf16 As[BM * LDK];
    __shared__ bf16 Bs[BN * LDK];
    int tid = threadIdx.x;
    int wave = tid >> 6, lane = tid & 63;
    int l15 = lane & 15, quad = lane >> 4;
    constexpr int WCOLS = BN / WN;
    int wr = wave / WCOLS, wc = wave % WCOLS;
    int m0 = blockIdx.y * BM, n0 = blockIdx.x * BN;
    constexpr int MI = WM / 16, NJ = WN / 16;
    floatx4 acc[MI][NJ];
    #pragma unroll
    for (int i = 0; i < MI; ++i)
        #pragma unroll
        for (int j = 0; j < NJ; ++j)
            acc[i][j] = (floatx4){0.f, 0.f, 0.f, 0.f};

    for (int k0 = 0; k0 < K; k0 += 32) {
        #pragma unroll
        for (int c = tid; c < BM * 4; c += 256) {
            int row = c >> 2, off = (c & 3) * 8;
            *(uint4*)&As[row * LDK + off] =
                *(const uint4*)&A[(size_t)(m0 + row) * K + k0 + off];
        }
        #pragma unroll
        for (int c = tid; c < BN * 4; c += 256) {
            int row = c >> 2, off = (c & 3) * 8;
            *(uint4*)&Bs[row * LDK + off] =
                *(const uint4*)&Bt[(size_t)(n0 + row) * K + k0 + off];
        }
        __syncthreads();
        short8 af[MI], bfr[NJ];
        #pragma unroll
        for (int i = 0; i < MI; ++i)
            af[i] = *(const short8*)&As[(wr * WM + i * 16 + l15) * LDK + quad * 8];
        #pragma unroll
        for (int j = 0; j < NJ; ++j)
            bfr[j] = *(const short8*)&Bs[(wc * WN + j * 16 + l15) * LDK + quad * 8];
        #pragma unroll
        for (int i = 0; i < MI; ++i)
            #pragma unroll
            for (int j = 0; j < NJ; ++j)
                acc[i][j] = __builtin_amdgcn_mfma_f32_16x16x32_bf16(af[i], bfr[j], acc[i][j], 0, 0, 0);
        __syncthreads();
    }
    #pragma unroll
    for (int i = 0; i < MI; ++i) {
        #pragma unroll
        for (int j = 0; j < NJ; ++j) {
            int nn = n0 + wc * WN + j * 16 + l15;
            float bv = bias[nn];
            #pragma unroll
            for (int rg = 0; rg < 4; ++rg) {
                int m = m0 + wr * WM + i * 16 + quad * 4 + rg;
                float v = acc[i][j][rg] + bv;
                if (R) v += R[(size_t)m * N + nn];
                if constexpr (sizeof(OutT) == 2)
                    D[(size_t)m * N + nn] = __float2bfloat16(v);
                else
                    D[(size_t)m * N + nn] = v;
            }
        }
    }
}

// ---- GEMM (N=128 full row) + residual + fused next-LayerNorm epilogue.
// BM=32, BN=128, 4 waves (WM=16 x WN=64). Writes Dres (fp32 residual stream)
// and Aout (LN-normalized bf16, A-operand of the next GEMM).
__global__ __launch_bounds__(256) void k_gemm_ln(const bf16* __restrict__ A,
                                                 const bf16* __restrict__ Bt,
                                                 const float* __restrict__ bias,
                                                 const float* __restrict__ R,
                                                 const float* __restrict__ g,
                                                 const float* __restrict__ be,
                                                 float* __restrict__ Dres,
                                                 bf16* __restrict__ Aout,
                                                 int K) {
    constexpr int LDK = 40;
    __shared__ bf16 As[32 * LDK];      // 2.5 KB
    __shared__ bf16 Bs[128 * LDK];     // 10 KB
    __shared__ float ot[32][132];      // 16.9 KB
    __shared__ float sG[128], sB[128]; // 1 KB
    int tid = threadIdx.x;
    int wave = tid >> 6, lane = tid & 63;
    int l15 = lane & 15, quad = lane >> 4;
    int wr = wave >> 1, wc = wave & 1;
    int m0 = blockIdx.x * 32;
    if (tid < 128) { sG[tid] = g[tid]; sB[tid] = be[tid]; }
    floatx4 acc[4];
    #pragma unroll
    for (int j = 0; j < 4; ++j) acc[j] = (floatx4){0.f, 0.f, 0.f, 0.f};

    for (int k0 = 0; k0 < K; k0 += 32) {
        if (tid < 128) {
            int row = tid >> 2, off = (tid & 3) * 8;
            *(uint4*)&As[row * LDK + off] =
                *(const uint4*)&A[(size_t)(m0 + row) * K + k0 + off];
        }
        #pragma unroll
        for (int c = tid; c < 512; c += 256) {
            int row = c >> 2, off = (c & 3) * 8;
            *(uint4*)&Bs[row * LDK + off] =
                *(const uint4*)&Bt[(size_t)row * K + k0 + off];
        }
        __syncthreads();
        short8 af = *(const short8*)&As[(wr * 16 + l15) * LDK + quad * 8];
        short8 bfr[4];
        #pragma unroll
        for (int j = 0; j < 4; ++j)
            bfr[j] = *(const short8*)&Bs[(wc * 64 + j * 16 + l15) * LDK + quad * 8];
        #pragma unroll
        for (int j = 0; j < 4; ++j)
            acc[j] = __builtin_amdgcn_mfma_f32_16x16x32_bf16(af, bfr[j], acc[j], 0, 0, 0);
        __syncthreads();
    }
    // v = acc + bias + R -> LDS tile
    #pragma unroll
    for (int j = 0; j < 4; ++j) {
        int nn = wc * 64 + j * 16 + l15;
        float bv = bias[nn];
        #pragma unroll
        for (int rg = 0; rg < 4; ++rg) {
            int m = wr * 16 + quad * 4 + rg;
            ot[m][nn] = acc[j][rg] + bv + R[(size_t)(m0 + m) * 128 + nn];
        }
    }
    __syncthreads();
    // row stats: 8 threads per row, 16 cols each
    int row = tid >> 3, sub = tid & 7;
    float vv[16];
    float s = 0.f, q = 0.f;
    #pragma unroll
    for (int i = 0; i < 16; ++i) {
        float v = ot[row][sub * 16 + i];
        vv[i] = v; s += v; q += v * v;
    }
    #pragma unroll
    for (int o = 4; o > 0; o >>= 1) { s += __shfl_xor(s, o); q += __shfl_xor(q, o); }
    float mean = s * (1.0f / 128.0f);
    float var = q * (1.0f / 128.0f) - mean * mean;
    float rst = rsqrtf(var + 1e-5f);
    size_t base = (size_t)(m0 + row) * 128 + sub * 16;
    #pragma unroll
    for (int i = 0; i < 16; i += 4)
        *(float4*)(Dres + base + i) = (float4){vv[i], vv[i+1], vv[i+2], vv[i+3]};
    #pragma unroll
    for (int i = 0; i < 16; i += 2) {
        int ch = sub * 16 + i;
        __hip_bfloat162 o2;
        o2.x = __float2bfloat16((vv[i]     - mean) * rst * sG[ch]     + sB[ch]);
        o2.y = __float2bfloat16((vv[i + 1] - mean) * rst * sG[ch + 1] + sB[ch + 1]);
        *(__hip_bfloat162*)(Aout + base + i) = o2;
    }
}

// ---- row-tiled 7x7 neighborhood attention; per-(xq,ky) logits, q from L2.
__global__ __launch_bounds__(256) void k_attn(const bf16* __restrict__ qkv,
                                              const float* __restrict__ rpb,
                                              bf16* __restrict__ out) {
    int blk = blockIdx.x;            // ((n*40 + y)*4 + head)
    int head = blk & 3;
    int ny = blk >> 2;
    int n = ny / 40, y = ny % 40;
    int sy = min(max(y - 3, 0), HH - 7);
    __shared__ bf16 KVs[7 * KVP];    // K then V, plane stride 1608 (22.5 KB)
    __shared__ float lg[40][49];     // 7.8 KB  -> total ~30.4 KB, 5 blocks/CU
    int tid = threadIdx.x;
    for (int i2 = tid; i2 < 1120; i2 += 256) {     // K window
        int d8 = i2 & 3, kx = (i2 >> 2) % 40, ky = i2 / 160;
        size_t base = ((size_t)(n * 1600 + (sy + ky) * 40 + kx)) * 384 + 128 + head * 32 + d8 * 8;
        *(uint4*)&KVs[ky * KVP + kx * 40 + d8 * 8] = *(const uint4*)(qkv + base);
    }
    __syncthreads();
    for (int p2 = tid; p2 < 280; p2 += 256) {      // logits: thread per (xq, ky)
        int xq = p2 / 7, ky = p2 - (p2 / 7) * 7;
        int sx = min(max(xq - 3, 0), WW - 7);
        // q direct from global (L2-hot, 7 threads share each token)
        const __hip_bfloat162* qp =
            (const __hip_bfloat162*)(qkv + ((size_t)(n * 1600 + y * 40 + xq)) * 384 + head * 32);
        float qf[32];
        #pragma unroll
        for (int c = 0; c < 16; ++c) {
            float2 f = __bfloat1622float2(qp[c]);
            qf[2 * c] = f.x; qf[2 * c + 1] = f.y;
        }
        const float* rb = rpb + head * 169 + (sy + ky - y + 6) * 13 + (sx - xq + 6);
        int kbase = ky * KVP + sx * 40;
        #pragma unroll
        for (int jx = 0; jx < 7; ++jx) {
            const __hip_bfloat162* kp = (const __hip_bfloat162*)&KVs[kbase + jx * 40];
            float dot = 0.f;
            #pragma unroll
            for (int c = 0; c < 16; ++c) {
                float2 kv = __bfloat1622float2(kp[c]);
                dot += qf[2 * c] * kv.x + qf[2 * c + 1] * kv.y;
            }
            lg[xq][ky * 7 + jx] = dot * 0.1767766952966369f + rb[jx];
        }
    }
    __syncthreads();
    for (int i2 = tid; i2 < 1120; i2 += 256) {     // V window (overwrite K)
        int d8 = i2 & 3, kx = (i2 >> 2) % 40, ky = i2 / 160;
        size_t base = ((size_t)(n * 1600 + (sy + ky) * 40 + kx)) * 384 + 256 + head * 32 + d8 * 8;
        *(uint4*)&KVs[ky * KVP + kx * 40 + d8 * 8] = *(const uint4*)(qkv + base);
    }
    if (tid < 40) {
        float m = -1e30f;
        for (int j = 0; j < 49; ++j) m = fmaxf(m, lg[tid][j]);
        float s = 0.f;
        for (int j = 0; j < 49; ++j) { float e = expf(lg[tid][j] - m); lg[tid][j] = e; s += e; }
        float inv = 1.0f / s;
        for (int j = 0; j < 49; ++j) lg[tid][j] *= inv;
    }
    __syncthreads();
    for (int o = tid; o < 640; o += 256) {         // PV reduce
        int xq = o >> 4, dp = (o & 15) * 2;
        int sx = min(max(xq - 3, 0), WW - 7);
        float a0 = 0.f, a1 = 0.f;
        #pragma unroll
        for (int ky = 0; ky < 7; ++ky) {
            int vbase = ky * KVP + sx * 40 + dp;
            #pragma unroll
            for (int jx = 0; jx < 7; ++jx) {
                float p = lg[xq][ky * 7 + jx];
                float2 v = __bfloat1622float2(*(const __hip_bfloat162*)&KVs[vbase + jx * 40]);
                a0 += p * v.x; a1 += p * v.y;
            }
        }
        __hip_bfloat162 o2;
        o2.x = __float2bfloat16(a0); o2.y = __float2bfloat16(a1);
        *(__hip_bfloat162*)(out + ((size_t)(n * 1600 + y * 40 + xq)) * 128 + head * 32 + dp) = o2;
    }
}

// ---- depthwise 3x3x3 conv + bias + exact GELU; fp32 in, bf16 out.
__global__ __launch_bounds__(512) void k_dwconv(const float* __restrict__ inp,
                                                const float* __restrict__ w,
                                                const float* __restrict__ bias,
                                                bf16* __restrict__ outp) {
    int blk = blockIdx.x;            // (n*40 + y)*2 + xh
    int xh = blk & 1;
    int ny = blk >> 1;
    int n = ny / 40, y = ny - n * 40;
    int b = n >> 3, t = n & 7;
    int m = threadIdx.x;
    float wr[27];
    #pragma unroll
    for (int i = 0; i < 27; ++i) wr[i] = w[i * 512 + m];
    float bs = bias[m];
    const float* rp[9];
    #pragma unroll
    for (int dt = 0; dt < 3; ++dt)
        #pragma unroll
        for (int dy = 0; dy < 3; ++dy) {
            int tt = t + dt - 1, yy = y + dy - 1;
            bool v = (tt >= 0 && tt < 8 && yy >= 0 && yy < 40);
            rp[dt * 3 + dy] = v ? inp + ((size_t)((b * 8 + tt) * 1600 + yy * 40)) * 512 + m
                                : nullptr;
        }
    int x0 = xh * 20;
    float c0[9], c1[9], c2[9];
    #pragma unroll
    for (int p = 0; p < 9; ++p) {
        c0[p] = (x0 > 0 && rp[p]) ? rp[p][(size_t)(x0 - 1) * 512] : 0.f;
        c1[p] = rp[p] ? rp[p][(size_t)x0 * 512] : 0.f;
    }
    size_t outbase = ((size_t)(n * 1600 + y * 40)) * 512 + m;
    for (int x = x0; x < x0 + 20; ++x) {
        #pragma unroll
        for (int p = 0; p < 9; ++p)
            c2[p] = (x < 39 && rp[p]) ? rp[p][(size_t)(x + 1) * 512] : 0.f;
        float acc = bs;
        #pragma unroll
        for (int p = 0; p < 9; ++p)
            acc += wr[p * 3 + 0] * c0[p] + wr[p * 3 + 1] * c1[p] + wr[p * 3 + 2] * c2[p];
        float g = 0.5f * acc * (1.0f + erff(acc * 0.70710678118654752f));
        outp[outbase + (size_t)x * 512] = __float2bfloat16(g);
        #pragma unroll
        for (int p = 0; p < 9; ++p) { c0[p] = c1[p]; c1[p] = c2[p]; }
    }
}

// ---- final LN + transpose via LDS tile, coalesced stores.
__global__ __launch_bounds__(256) void k_ln_out(const float* __restrict__ src,
                                                const float* __restrict__ gamma,
                                                const float* __restrict__ beta,
                                                float* __restrict__ out) {
    int blk = blockIdx.x;
    int n = blk / 50, ri = blk % 50;
    int r0 = ri * 32;
    int b = n >> 3, t = n & 7;
    __shared__ float tile[128][33];
    int tid = threadIdx.x;
    int tok = tid >> 3, sub = tid & 7;
    const float* sp = src + ((size_t)(n * 1600 + r0 + tok)) * 128 + sub * 16;
    float v[16];
    float s = 0.f, q = 0.f;
    #pragma unroll
    for (int i = 0; i < 16; i += 4) {
        float4 f = *(const float4*)(sp + i);
        v[i] = f.x; v[i + 1] = f.y; v[i + 2] = f.z; v[i + 3] = f.w;
        s += f.x + f.y + f.z + f.w;
        q += f.x * f.x + f.y * f.y + f.z * f.z + f.w * f.w;
    }
    #pragma unroll
    for (int o = 4; o > 0; o >>= 1) { s += __shfl_xor(s, o); q += __shfl_xor(q, o); }
    float mean = s * (1.0f / 128.0f);
    float var = q * (1.0f / 128.0f) - mean * mean;
    float inv = rsqrtf(var + 1e-5f);
    #pragma unroll
    for (int i = 0; i < 16; ++i) {
        int ch = sub * 16 + i;
        tile[ch][tok] = (v[i] - mean) * inv * gamma[ch] + beta[ch];
    }
    __syncthreads();
    #pragma unroll
    for (int it = 0; it < 16; ++it) {
        int idx = it * 256 + tid;
        int ch = idx >> 5, tk = idx & 31;
        out[((size_t)((b * 128 + ch) * 8 + t)) * 1600 + r0 + tk] = tile[ch][tk];
    }
}

extern "C" void kernel_launch(void* const* d_in, const int* in_sizes, int n_in,
                              void* d_out, int out_size, void* d_ws, size_t ws_size,
                              hipStream_t stream) {
    const float* x      = (const float*)d_in[0];
    const float* ln1_g  = (const float*)d_in[1];
    const float* ln1_b  = (const float*)d_in[2];
    const float* qkv_w  = (const float*)d_in[3];
    const float* qkv_b  = (const float*)d_in[4];
    const float* rpb    = (const float*)d_in[5];
    const float* proj_w = (const float*)d_in[6];
    const float* proj_b = (const float*)d_in[7];
    const float* ln2_g  = (const float*)d_in[8];
    const float* ln2_b  = (const float*)d_in[9];
    const float* fc1_w  = (const float*)d_in[10];
    const float* fc1_b  = (const float*)d_in[11];
    const float* dw_w   = (const float*)d_in[12];
    const float* dw_b   = (const float*)d_in[13];
    const float* fc2_w  = (const float*)d_in[14];
    const float* fc2_b  = (const float*)d_in[15];
    const float* out_g  = (const float*)d_in[16];
    const float* out_b  = (const float*)d_in[17];
    float* out = (float*)d_out;

    // workspace: h f32 | f1 f32 | qkvb bf16 | f2b bf16 | abufA bf16 | abufL bf16 | wt
    float* h     = (float*)d_ws;
    float* f1    = h + (size_t)NTOK * 128;
    bf16* qkvb   = (bf16*)(f1 + (size_t)NTOK * 512);
    bf16* f2b    = qkvb + (size_t)NTOK * 384;
    bf16* abufA  = f2b  + (size_t)NTOK * 512;
    bf16* abufL  = abufA + (size_t)NTOK * 128;
    bf16* wt     = abufL + (size_t)NTOK * 128;

    k_wt<<<96, 256, 0, stream>>>(qkv_w, proj_w, fc1_w, fc2_w, wt);
    k_transpose_in<<<NIMG * 200, 256, 0, stream>>>(x, h);
    for (int l = 0; l < 2; ++l) {
        const bf16* wtl = wt + (size_t)l * WT_L;
        if (l == 0) {
            k_lngemm<bf16><<<dim3(3, 400), 256, 0, stream>>>(
                h, wtl + WT_QKV, ln1_g, ln1_b, qkv_b, qkvb, 384);
        } else {
            k_gemm_mfma<64, 128, 32, 64, bf16><<<dim3(3, 400), 256, 0, stream>>>(
                abufL, wtl + WT_QKV, qkv_b + 384, nullptr, qkvb, 128, 384);
        }
        k_attn<<<NIMG * HH * NHEAD, 256, 0, stream>>>(qkvb, rpb + l * 4 * 169, abufA);
        // proj + residual + fused LN2 epilogue -> abufL
        k_gemm_ln<<<800, 256, 0, stream>>>(
            abufA, wtl + WT_PROJ, proj_b + l * 128, h,
            ln2_g + l * 128, ln2_b + l * 128, h, abufL, 128);
        // fc1: plain bf16-A GEMM
        k_gemm_mfma<64, 128, 32, 64, float><<<dim3(4, 400), 256, 0, stream>>>(
            abufL, wtl + WT_FC1, fc1_b + l * 512, nullptr, f1, 128, 512);
        k_dwconv<<<NIMG * HH * 2, 512, 0, stream>>>(f1, dw_w + l * 27 * 512, dw_b + l * 512, f2b);
        if (l == 0) {
            // fc2 + residual + fused LN1(layer 1) epilogue -> abufL
            k_gemm_ln<<<800, 256, 0, stream>>>(
                f2b, wtl + WT_FC2, fc2_b, h,
                ln1_g + 128, ln1_b + 128, h, abufL, 512);
        } else {
            k_gemm_mfma<32, 128, 16, 64, float><<<dim3(1, 800), 256, 0, stream>>>(
                f2b, wtl + WT_FC2, fc2_b + 128, h, h, 512, 128);
        }
    }
    k_ln_out<<<NIMG * 50, 256, 0, stream>>>(h, out_g, out_b, out);
}

// Round 12
// 419.242 us; speedup vs baseline: 1.3720x; 1.0201x over previous
//
#include <hip/hip_runtime.h>
#include <hip/hip_bf16.h>
#include <math.h>

typedef __hip_bfloat16 bf16;
typedef __attribute__((ext_vector_type(8))) short short8;
typedef __attribute__((ext_vector_type(4))) float floatx4;
typedef _Float16 h2 __attribute__((ext_vector_type(2)));

#define HH 40
#define WW 40
#define CC 128
#define TT 8
#define NIMG 16           // B*T
#define NTOK 25600        // NIMG*HH*WW
#define MDIM 512
#define NHEAD 4
#define KVP 1608          // K/V LDS plane stride in elems

// weight-transpose buffer offsets (bf16 elems), per layer
#define WT_QKV 0
#define WT_PROJ 49152
#define WT_FC1  65536
#define WT_FC2  131072
#define WT_L    196608

// ---- input transpose via LDS tiles: x (b,c,t,y,x) -> h (n,y,x,c), both coalesced.
__global__ __launch_bounds__(256) void k_transpose_in(const float* __restrict__ x,
                                                      float* __restrict__ h) {
    int blk = blockIdx.x;
    int n = blk / 200; int r = blk % 200; int ci = r / 50, ri = r % 50;
    int b = n >> 3, t = n & 7;
    int c0 = ci * 32, r0 = ri * 32;
    __shared__ float tile[32][33];
    int tid = threadIdx.x;
    int lc = tid >> 5, lr = tid & 31;         // 8 x 32
    #pragma unroll
    for (int it = 0; it < 4; ++it) {
        int cc = it * 8 + lc;
        tile[cc][lr] = x[((size_t)((b * 128 + c0 + cc) * 8 + t)) * 1600 + r0 + lr];
    }
    __syncthreads();
    #pragma unroll
    for (int it = 0; it < 4; ++it) {
        int rr = it * 8 + lc;
        h[((size_t)(n * 1600 + r0 + rr)) * 128 + c0 + lr] = tile[lr][rr];
    }
}

// ---- weight convert+transpose: W[K,N] fp32 -> Wt[N,K] bf16, 64x64 LDS tiles.
__global__ __launch_bounds__(256) void k_wt(const float* __restrict__ qkv_w,
                                            const float* __restrict__ proj_w,
                                            const float* __restrict__ fc1_w,
                                            const float* __restrict__ fc2_w,
                                            bf16* __restrict__ wt) {
    __shared__ float tile[64][65];
    int id = blockIdx.x;
    int l = id / 48, r = id % 48;
    const float* src; bf16* dst; int K_, N_, t;
    if (r < 12)      { src = qkv_w  + l * 128 * 384; dst = wt + l * WT_L + WT_QKV; K_ = 128; N_ = 384; t = r; }
    else if (r < 16) { src = proj_w + l * 128 * 128; dst = wt + l * WT_L + WT_PROJ; K_ = 128; N_ = 128; t = r - 12; }
    else if (r < 32) { src = fc1_w  + l * 128 * 512; dst = wt + l * WT_L + WT_FC1; K_ = 128; N_ = 512; t = r - 16; }
    else             { src = fc2_w  + l * 512 * 128; dst = wt + l * WT_L + WT_FC2; K_ = 512; N_ = 128; t = r - 32; }
    int KT = K_ >> 6;
    int k0 = (t % KT) * 64, n0 = (t / KT) * 64;
    int tid = threadIdx.x;
    for (int c = tid; c < 4096; c += 256) {
        int kk = c >> 6, nn = c & 63;
        tile[kk][nn] = src[(size_t)(k0 + kk) * N_ + n0 + nn];
    }
    __syncthreads();
    for (int c = tid; c < 4096; c += 256) {
        int nn = c >> 6, kk = c & 63;
        dst[(size_t)(n0 + nn) * K_ + k0 + kk] = __float2bfloat16(tile[kk][nn]);
    }
}

// ---- fused LayerNorm + MFMA GEMM (fp32 A): only layer-0 qkv.
template<typename OutT>
__global__ __launch_bounds__(256) void k_lngemm(const float* __restrict__ A,
                                                const bf16* __restrict__ Bt,
                                                const float* __restrict__ g,
                                                const float* __restrict__ be,
                                                const float* __restrict__ bias,
                                                OutT* __restrict__ D,
                                                int N) {
    constexpr int LDK = 40;
    __shared__ bf16 As[64 * LDK];
    __shared__ bf16 Bs[128 * LDK];
    __shared__ float sMean[64], sRstd[64], sG[128], sB[128];
    int tid = threadIdx.x;
    int m0 = blockIdx.y * 64, n0 = blockIdx.x * 128;
    {
        int row = tid >> 2, q4 = tid & 3;
        const float* p = A + (size_t)(m0 + row) * 128 + q4 * 32;
        float s = 0.f, q = 0.f;
        #pragma unroll
        for (int i = 0; i < 32; i += 4) {
            float4 f = *(const float4*)(p + i);
            s += f.x + f.y + f.z + f.w;
            q += f.x * f.x + f.y * f.y + f.z * f.z + f.w * f.w;
        }
        s += __shfl_xor(s, 1); q += __shfl_xor(q, 1);
        s += __shfl_xor(s, 2); q += __shfl_xor(q, 2);
        if (q4 == 0) {
            float mean = s * (1.0f / 128.0f);
            float var = q * (1.0f / 128.0f) - mean * mean;
            sMean[row] = mean;
            sRstd[row] = rsqrtf(var + 1e-5f);
        }
        if (tid < 128) { sG[tid] = g[tid]; sB[tid] = be[tid]; }
    }
    __syncthreads();
    int wave = tid >> 6, lane = tid & 63;
    int l15 = lane & 15, quad = lane >> 4;
    int wr = wave >> 1, wc = wave & 1;
    floatx4 acc[2][4];
    #pragma unroll
    for (int i = 0; i < 2; ++i)
        #pragma unroll
        for (int j = 0; j < 4; ++j)
            acc[i][j] = (floatx4){0.f, 0.f, 0.f, 0.f};

    for (int k0 = 0; k0 < 128; k0 += 32) {
        #pragma unroll
        for (int it = 0; it < 2; ++it) {
            int c = tid + it * 256;
            int row = c >> 3, kq = (c & 7) * 4;
            float4 f = *(const float4*)(A + (size_t)(m0 + row) * 128 + k0 + kq);
            float mean = sMean[row], rst = sRstd[row];
            float r0v = (f.x - mean) * rst * sG[k0 + kq]     + sB[k0 + kq];
            float r1v = (f.y - mean) * rst * sG[k0 + kq + 1] + sB[k0 + kq + 1];
            float r2v = (f.z - mean) * rst * sG[k0 + kq + 2] + sB[k0 + kq + 2];
            float r3v = (f.w - mean) * rst * sG[k0 + kq + 3] + sB[k0 + kq + 3];
            __hip_bfloat162 p0, p1;
            p0.x = __float2bfloat16(r0v); p0.y = __float2bfloat16(r1v);
            p1.x = __float2bfloat16(r2v); p1.y = __float2bfloat16(r3v);
            *(__hip_bfloat162*)&As[row * LDK + kq]     = p0;
            *(__hip_bfloat162*)&As[row * LDK + kq + 2] = p1;
        }
        #pragma unroll
        for (int c = tid; c < 512; c += 256) {
            int row = c >> 2, off = (c & 3) * 8;
            *(uint4*)&Bs[row * LDK + off] =
                *(const uint4*)&Bt[(size_t)(n0 + row) * 128 + k0 + off];
        }
        __syncthreads();
        short8 af[2], bfr[4];
        #pragma unroll
        for (int i = 0; i < 2; ++i)
            af[i] = *(const short8*)&As[(wr * 32 + i * 16 + l15) * LDK + quad * 8];
        #pragma unroll
        for (int j = 0; j < 4; ++j)
            bfr[j] = *(const short8*)&Bs[(wc * 64 + j * 16 + l15) * LDK + quad * 8];
        #pragma unroll
        for (int i = 0; i < 2; ++i)
            #pragma unroll
            for (int j = 0; j < 4; ++j)
                acc[i][j] = __builtin_amdgcn_mfma_f32_16x16x32_bf16(af[i], bfr[j], acc[i][j], 0, 0, 0);
        __syncthreads();
    }
    #pragma unroll
    for (int i = 0; i < 2; ++i) {
        #pragma unroll
        for (int j = 0; j < 4; ++j) {
            int nn = n0 + wc * 64 + j * 16 + l15;
            float bv = bias[nn];
            #pragma unroll
            for (int rg = 0; rg < 4; ++rg) {
                int m = m0 + wr * 32 + i * 16 + quad * 4 + rg;
                float v = acc[i][j][rg] + bv;
                if constexpr (sizeof(OutT) == 2)
                    D[(size_t)m * N + nn] = __float2bfloat16(v);
                else
                    D[(size_t)m * N + nn] = v;
            }
        }
    }
}

// ---- MFMA bf16 GEMM: D[M,N] = A[M,K] @ Bt[N,K]^T + bias (+R).
template<int BM, int BN, int WM, int WN, typename OutT>
__global__ __launch_bounds__(256) void k_gemm_mfma(const bf16* __restrict__ A,
                                                   const bf16* __restrict__ Bt,
                                                   const float* __restrict__ bias,
                                                   const float* __restrict__ R,
                                                   OutT* __restrict__ D,
                                                   int K, int N) {
    constexpr int LDK = 40;
    __shared__ bf16 As[BM * LDK];
    __shared__ bf16 Bs[BN * LDK];
    int tid = threadIdx.x;
    int wave = tid >> 6, lane = tid & 63;
    int l15 = lane & 15, quad = lane >> 4;
    constexpr int WCOLS = BN / WN;
    int wr = wave / WCOLS, wc = wave % WCOLS;
    int m0 = blockIdx.y * BM, n0 = blockIdx.x * BN;
    constexpr int MI = WM / 16, NJ = WN / 16;
    floatx4 acc[MI][NJ];
    #pragma unroll
    for (int i = 0; i < MI; ++i)
        #pragma unroll
        for (int j = 0; j < NJ; ++j)
            acc[i][j] = (floatx4){0.f, 0.f, 0.f, 0.f};

    for (int k0 = 0; k0 < K; k0 += 32) {
        #pragma unroll
        for (int c = tid; c < BM * 4; c += 256) {
            int row = c >> 2, off = (c & 3) * 8;
            *(uint4*)&As[row * LDK + off] =
                *(const uint4*)&A[(size_t)(m0 + row) * K + k0 + off];
        }
        #pragma unroll
        for (int c = tid; c < BN * 4; c += 256) {
            int row = c >> 2, off = (c & 3) * 8;
            *(uint4*)&Bs[row * LDK + off] =
                *(const uint4*)&Bt[(size_t)(n0 + row) * K + k0 + off];
        }
        __syncthreads();
        short8 af[MI], bfr[NJ];
        #pragma unroll
        for (int i = 0; i < MI; ++i)
            af[i] = *(const short8*)&As[(wr * WM + i * 16 + l15) * LDK + quad * 8];
        #pragma unroll
        for (int j = 0; j < NJ; ++j)
            bfr[j] = *(const short8*)&Bs[(wc * WN + j * 16 + l15) * LDK + quad * 8];
        #pragma unroll
        for (int i = 0; i < MI; ++i)
            #pragma unroll
            for (int j = 0; j < NJ; ++j)
                acc[i][j] = __builtin_amdgcn_mfma_f32_16x16x32_bf16(af[i], bfr[j], acc[i][j], 0, 0, 0);
        __syncthreads();
    }
    #pragma unroll
    for (int i = 0; i < MI; ++i) {
        #pragma unroll
        for (int j = 0; j < NJ; ++j) {
            int nn = n0 + wc * WN + j * 16 + l15;
            float bv = bias[nn];
            #pragma unroll
            for (int rg = 0; rg < 4; ++rg) {
                int m = m0 + wr * WM + i * 16 + quad * 4 + rg;
                float v = acc[i][j][rg] + bv;
                if (R) v += R[(size_t)m * N + nn];
                if constexpr (sizeof(OutT) == 2)
                    D[(size_t)m * N + nn] = __float2bfloat16(v);
                else
                    D[(size_t)m * N + nn] = v;
            }
        }
    }
}

// ---- GEMM (N=128) + residual + fused next-LayerNorm epilogue.
// Writes Dres (fp32 residual) and Aout (LN'd bf16 A-operand for next GEMM).
__global__ __launch_bounds__(256) void k_gemm_ln(const bf16* __restrict__ A,
                                                 const bf16* __restrict__ Bt,
                                                 const float* __restrict__ bias,
                                                 const float* __restrict__ R,
                                                 const float* __restrict__ g,
                                                 const float* __restrict__ be,
                                                 float* __restrict__ Dres,
                                                 bf16* __restrict__ Aout,
                                                 int K) {
    constexpr int LDK = 40;
    __shared__ bf16 As[32 * LDK];
    __shared__ bf16 Bs[128 * LDK];
    __shared__ float ot[32][132];
    __shared__ float sG[128], sB[128];
    int tid = threadIdx.x;
    int wave = tid >> 6, lane = tid & 63;
    int l15 = lane & 15, quad = lane >> 4;
    int wr = wave >> 1, wc = wave & 1;
    int m0 = blockIdx.x * 32;
    if (tid < 128) { sG[tid] = g[tid]; sB[tid] = be[tid]; }
    floatx4 acc[4];
    #pragma unroll
    for (int j = 0; j < 4; ++j) acc[j] = (floatx4){0.f, 0.f, 0.f, 0.f};

    for (int k0 = 0; k0 < K; k0 += 32) {
        if (tid < 128) {
            int row = tid >> 2, off = (tid & 3) * 8;
            *(uint4*)&As[row * LDK + off] =
                *(const uint4*)&A[(size_t)(m0 + row) * K + k0 + off];
        }
        #pragma unroll
        for (int c = tid; c < 512; c += 256) {
            int row = c >> 2, off = (c & 3) * 8;
            *(uint4*)&Bs[row * LDK + off] =
                *(const uint4*)&Bt[(size_t)row * K + k0 + off];
        }
        __syncthreads();
        short8 af = *(const short8*)&As[(wr * 16 + l15) * LDK + quad * 8];
        short8 bfr[4];
        #pragma unroll
        for (int j = 0; j < 4; ++j)
            bfr[j] = *(const short8*)&Bs[(wc * 64 + j * 16 + l15) * LDK + quad * 8];
        #pragma unroll
        for (int j = 0; j < 4; ++j)
            acc[j] = __builtin_amdgcn_mfma_f32_16x16x32_bf16(af, bfr[j], acc[j], 0, 0, 0);
        __syncthreads();
    }
    #pragma unroll
    for (int j = 0; j < 4; ++j) {
        int nn = wc * 64 + j * 16 + l15;
        float bv = bias[nn];
        #pragma unroll
        for (int rg = 0; rg < 4; ++rg) {
            int m = wr * 16 + quad * 4 + rg;
            ot[m][nn] = acc[j][rg] + bv + R[(size_t)(m0 + m) * 128 + nn];
        }
    }
    __syncthreads();
    int row = tid >> 3, sub = tid & 7;
    float vv[16];
    float s = 0.f, q = 0.f;
    #pragma unroll
    for (int i = 0; i < 16; ++i) {
        float v = ot[row][sub * 16 + i];
        vv[i] = v; s += v; q += v * v;
    }
    #pragma unroll
    for (int o = 4; o > 0; o >>= 1) { s += __shfl_xor(s, o); q += __shfl_xor(q, o); }
    float mean = s * (1.0f / 128.0f);
    float var = q * (1.0f / 128.0f) - mean * mean;
    float rst = rsqrtf(var + 1e-5f);
    size_t base = (size_t)(m0 + row) * 128 + sub * 16;
    #pragma unroll
    for (int i = 0; i < 16; i += 4)
        *(float4*)(Dres + base + i) = (float4){vv[i], vv[i+1], vv[i+2], vv[i+3]};
    #pragma unroll
    for (int i = 0; i < 16; i += 2) {
        int ch = sub * 16 + i;
        __hip_bfloat162 o2;
        o2.x = __float2bfloat16((vv[i]     - mean) * rst * sG[ch]     + sB[ch]);
        o2.y = __float2bfloat16((vv[i + 1] - mean) * rst * sG[ch + 1] + sB[ch + 1]);
        *(__hip_bfloat162*)(Aout + base + i) = o2;
    }
}

// ---- GEMM (N=128) + residual + FINAL LayerNorm + transposed store to (b,c,t,y,x).
// BM=32 rows all share one image n (1600 % 32 == 0).
__global__ __launch_bounds__(256) void k_gemm_lnout(const bf16* __restrict__ A,
                                                    const bf16* __restrict__ Bt,
                                                    const float* __restrict__ bias,
                                                    const float* __restrict__ R,
                                                    const float* __restrict__ g,
                                                    const float* __restrict__ be,
                                                    float* __restrict__ out,
                                                    int K) {
    constexpr int LDK = 40;
    __shared__ bf16 As[32 * LDK];
    __shared__ bf16 Bs[128 * LDK];
    __shared__ float ot[32][133];    // pad 133: conflict-free transposed reads
    __shared__ float sG[128], sB[128];
    int tid = threadIdx.x;
    int wave = tid >> 6, lane = tid & 63;
    int l15 = lane & 15, quad = lane >> 4;
    int wr = wave >> 1, wc = wave & 1;
    int m0 = blockIdx.x * 32;
    if (tid < 128) { sG[tid] = g[tid]; sB[tid] = be[tid]; }
    floatx4 acc[4];
    #pragma unroll
    for (int j = 0; j < 4; ++j) acc[j] = (floatx4){0.f, 0.f, 0.f, 0.f};

    for (int k0 = 0; k0 < K; k0 += 32) {
        if (tid < 128) {
            int row = tid >> 2, off = (tid & 3) * 8;
            *(uint4*)&As[row * LDK + off] =
                *(const uint4*)&A[(size_t)(m0 + row) * K + k0 + off];
        }
        #pragma unroll
        for (int c = tid; c < 512; c += 256) {
            int row = c >> 2, off = (c & 3) * 8;
            *(uint4*)&Bs[row * LDK + off] =
                *(const uint4*)&Bt[(size_t)row * K + k0 + off];
        }
        __syncthreads();
        short8 af = *(const short8*)&As[(wr * 16 + l15) * LDK + quad * 8];
        short8 bfr[4];
        #pragma unroll
        for (int j = 0; j < 4; ++j)
            bfr[j] = *(const short8*)&Bs[(wc * 64 + j * 16 + l15) * LDK + quad * 8];
        #pragma unroll
        for (int j = 0; j < 4; ++j)
            acc[j] = __builtin_amdgcn_mfma_f32_16x16x32_bf16(af, bfr[j], acc[j], 0, 0, 0);
        __syncthreads();
    }
    #pragma unroll
    for (int j = 0; j < 4; ++j) {
        int nn = wc * 64 + j * 16 + l15;
        float bv = bias[nn];
        #pragma unroll
        for (int rg = 0; rg < 4; ++rg) {
            int m = wr * 16 + quad * 4 + rg;
            ot[m][nn] = acc[j][rg] + bv + R[(size_t)(m0 + m) * 128 + nn];
        }
    }
    __syncthreads();
    int row = tid >> 3, sub = tid & 7;
    float vv[16];
    float s = 0.f, q = 0.f;
    #pragma unroll
    for (int i = 0; i < 16; ++i) {
        float v = ot[row][sub * 16 + i];
        vv[i] = v; s += v; q += v * v;
    }
    #pragma unroll
    for (int o = 4; o > 0; o >>= 1) { s += __shfl_xor(s, o); q += __shfl_xor(q, o); }
    float mean = s * (1.0f / 128.0f);
    float var = q * (1.0f / 128.0f) - mean * mean;
    float rst = rsqrtf(var + 1e-5f);
    #pragma unroll
    for (int i = 0; i < 16; ++i) {
        int ch = sub * 16 + i;
        ot[row][ch] = (vv[i] - mean) * rst * sG[ch] + sB[ch];
    }
    __syncthreads();
    // transposed store: all 32 tokens share n
    int n = m0 / 1600, rem0 = m0 % 1600;
    int b = n >> 3, t = n & 7;
    #pragma unroll
    for (int it = 0; it < 16; ++it) {
        int idx = it * 256 + tid;
        int ch = idx >> 5, tk = idx & 31;
        out[((size_t)((b * 128 + ch) * 8 + t)) * 1600 + rem0 + tk] = ot[tk][ch];
    }
}

// ---- row-tiled 7x7 neighborhood attention; f16 K + fdot2 logits, bf16 V.
__global__ __launch_bounds__(256) void k_attn(const bf16* __restrict__ qkv,
                                              const float* __restrict__ rpb,
                                              bf16* __restrict__ out) {
    int blk = blockIdx.x;            // ((n*40 + y)*4 + head)
    int head = blk & 3;
    int ny = blk >> 2;
    int n = ny / 40, y = ny % 40;
    int sy = min(max(y - 3, 0), HH - 7);
    __shared__ __align__(16) short KVs[7 * KVP];   // K (f16) then V (bf16)
    __shared__ float lg[40][49];
    int tid = threadIdx.x;
    // phase 1: K window, bf16 -> f16 in staging
    for (int i2 = tid; i2 < 1120; i2 += 256) {
        int d8 = i2 & 3, kx = (i2 >> 2) % 40, ky = i2 / 160;
        size_t base = ((size_t)(n * 1600 + (sy + ky) * 40 + kx)) * 384 + 128 + head * 32 + d8 * 8;
        union { uint4 u; __hip_bfloat162 b[4]; } U;
        U.u = *(const uint4*)(qkv + base);
        short* dst = &KVs[ky * KVP + kx * 40 + d8 * 8];
        #pragma unroll
        for (int c = 0; c < 4; ++c) {
            float2 f = __bfloat1622float2(U.b[c]);
            h2 hv; hv.x = (_Float16)f.x; hv.y = (_Float16)f.y;
            *(h2*)(dst + 2 * c) = hv;
        }
    }
    __syncthreads();
    // logits: thread per (xq, ky); q from global (L2-hot), converted to f16 pairs
    for (int p2 = tid; p2 < 280; p2 += 256) {
        int xq = p2 / 7, ky = p2 - (p2 / 7) * 7;
        int sx = min(max(xq - 3, 0), WW - 7);
        const __hip_bfloat162* qp =
            (const __hip_bfloat162*)(qkv + ((size_t)(n * 1600 + y * 40 + xq)) * 384 + head * 32);
        h2 qh[16];
        #pragma unroll
        for (int c = 0; c < 16; ++c) {
            float2 f = __bfloat1622float2(qp[c]);
            qh[c].x = (_Float16)f.x; qh[c].y = (_Float16)f.y;
        }
        const float* rb = rpb + head * 169 + (sy + ky - y + 6) * 13 + (sx - xq + 6);
        int kbase = ky * KVP + sx * 40;
        #pragma unroll
        for (int jx = 0; jx < 7; ++jx) {
            const h2* kp = (const h2*)&KVs[kbase + jx * 40];
            float dot = 0.f;
            #pragma unroll
            for (int c = 0; c < 16; ++c)
                dot = __builtin_amdgcn_fdot2(qh[c], kp[c], dot, false);
            lg[xq][ky * 7 + jx] = dot * 0.1767766952966369f + rb[jx];
        }
    }
    __syncthreads();
    // phase 2: V window (raw bf16 bits), softmax concurrently
    for (int i2 = tid; i2 < 1120; i2 += 256) {
        int d8 = i2 & 3, kx = (i2 >> 2) % 40, ky = i2 / 160;
        size_t base = ((size_t)(n * 1600 + (sy + ky) * 40 + kx)) * 384 + 256 + head * 32 + d8 * 8;
        *(uint4*)&KVs[ky * KVP + kx * 40 + d8 * 8] = *(const uint4*)(qkv + base);
    }
    if (tid < 40) {
        float m = -1e30f;
        for (int j = 0; j < 49; ++j) m = fmaxf(m, lg[tid][j]);
        float s = 0.f;
        for (int j = 0; j < 49; ++j) { float e = expf(lg[tid][j] - m); lg[tid][j] = e; s += e; }
        float inv = 1.0f / s;
        for (int j = 0; j < 49; ++j) lg[tid][j] *= inv;
    }
    __syncthreads();
    for (int o = tid; o < 640; o += 256) {         // PV reduce (bf16 V)
        int xq = o >> 4, dp = (o & 15) * 2;
        int sx = min(max(xq - 3, 0), WW - 7);
        float a0 = 0.f, a1 = 0.f;
        #pragma unroll
        for (int ky = 0; ky < 7; ++ky) {
            int vbase = ky * KVP + sx * 40 + dp;
            #pragma unroll
            for (int jx = 0; jx < 7; ++jx) {
                float p = lg[xq][ky * 7 + jx];
                float2 v = __bfloat1622float2(*(const __hip_bfloat162*)&KVs[vbase + jx * 40]);
                a0 += p * v.x; a1 += p * v.y;
            }
        }
        __hip_bfloat162 o2;
        o2.x = __float2bfloat16(a0); o2.y = __float2bfloat16(a1);
        *(__hip_bfloat162*)(out + ((size_t)(n * 1600 + y * 40 + xq)) * 128 + head * 32 + dp) = o2;
    }
}

// ---- depthwise 3x3x3 conv + bias + exact GELU; fp32 in, bf16 out.
__global__ __launch_bounds__(512) void k_dwconv(const float* __restrict__ inp,
                                                const float* __restrict__ w,
                                                const float* __restrict__ bias,
                                                bf16* __restrict__ outp) {
    int blk = blockIdx.x;            // (n*40 + y)*2 + xh
    int xh = blk & 1;
    int ny = blk >> 1;
    int n = ny / 40, y = ny - n * 40;
    int b = n >> 3, t = n & 7;
    int m = threadIdx.x;
    float wr[27];
    #pragma unroll
    for (int i = 0; i < 27; ++i) wr[i] = w[i * 512 + m];
    float bs = bias[m];
    const float* rp[9];
    #pragma unroll
    for (int dt = 0; dt < 3; ++dt)
        #pragma unroll
        for (int dy = 0; dy < 3; ++dy) {
            int tt = t + dt - 1, yy = y + dy - 1;
            bool v = (tt >= 0 && tt < 8 && yy >= 0 && yy < 40);
            rp[dt * 3 + dy] = v ? inp + ((size_t)((b * 8 + tt) * 1600 + yy * 40)) * 512 + m
                                : nullptr;
        }
    int x0 = xh * 20;
    float c0[9], c1[9], c2[9];
    #pragma unroll
    for (int p = 0; p < 9; ++p) {
        c0[p] = (x0 > 0 && rp[p]) ? rp[p][(size_t)(x0 - 1) * 512] : 0.f;
        c1[p] = rp[p] ? rp[p][(size_t)x0 * 512] : 0.f;
    }
    size_t outbase = ((size_t)(n * 1600 + y * 40)) * 512 + m;
    for (int x = x0; x < x0 + 20; ++x) {
        #pragma unroll
        for (int p = 0; p < 9; ++p)
            c2[p] = (x < 39 && rp[p]) ? rp[p][(size_t)(x + 1) * 512] : 0.f;
        float acc = bs;
        #pragma unroll
        for (int p = 0; p < 9; ++p)
            acc += wr[p * 3 + 0] * c0[p] + wr[p * 3 + 1] * c1[p] + wr[p * 3 + 2] * c2[p];
        float g = 0.5f * acc * (1.0f + erff(acc * 0.70710678118654752f));
        outp[outbase + (size_t)x * 512] = __float2bfloat16(g);
        #pragma unroll
        for (int p = 0; p < 9; ++p) { c0[p] = c1[p]; c1[p] = c2[p]; }
    }
}

extern "C" void kernel_launch(void* const* d_in, const int* in_sizes, int n_in,
                              void* d_out, int out_size, void* d_ws, size_t ws_size,
                              hipStream_t stream) {
    const float* x      = (const float*)d_in[0];
    const float* ln1_g  = (const float*)d_in[1];
    const float* ln1_b  = (const float*)d_in[2];
    const float* qkv_w  = (const float*)d_in[3];
    const float* qkv_b  = (const float*)d_in[4];
    const float* rpb    = (const float*)d_in[5];
    const float* proj_w = (const float*)d_in[6];
    const float* proj_b = (const float*)d_in[7];
    const float* ln2_g  = (const float*)d_in[8];
    const float* ln2_b  = (const float*)d_in[9];
    const float* fc1_w  = (const float*)d_in[10];
    const float* fc1_b  = (const float*)d_in[11];
    const float* dw_w   = (const float*)d_in[12];
    const float* dw_b   = (const float*)d_in[13];
    const float* fc2_w  = (const float*)d_in[14];
    const float* fc2_b  = (const float*)d_in[15];
    const float* out_g  = (const float*)d_in[16];
    const float* out_b  = (const float*)d_in[17];
    float* out = (float*)d_out;

    // workspace: h f32 | f1 f32 | qkvb bf16 | f2b bf16 | abufA bf16 | abufL bf16 | wt
    float* h     = (float*)d_ws;
    float* f1    = h + (size_t)NTOK * 128;
    bf16* qkvb   = (bf16*)(f1 + (size_t)NTOK * 512);
    bf16* f2b    = qkvb + (size_t)NTOK * 384;
    bf16* abufA  = f2b  + (size_t)NTOK * 512;
    bf16* abufL  = abufA + (size_t)NTOK * 128;
    bf16* wt     = abufL + (size_t)NTOK * 128;

    k_wt<<<96, 256, 0, stream>>>(qkv_w, proj_w, fc1_w, fc2_w, wt);
    k_transpose_in<<<NIMG * 200, 256, 0, stream>>>(x, h);
    for (int l = 0; l < 2; ++l) {
        const bf16* wtl = wt + (size_t)l * WT_L;
        if (l == 0) {
            k_lngemm<bf16><<<dim3(3, 400), 256, 0, stream>>>(
                h, wtl + WT_QKV, ln1_g, ln1_b, qkv_b, qkvb, 384);
        } else {
            k_gemm_mfma<64, 128, 32, 64, bf16><<<dim3(3, 400), 256, 0, stream>>>(
                abufL, wtl + WT_QKV, qkv_b + 384, nullptr, qkvb, 128, 384);
        }
        k_attn<<<NIMG * HH * NHEAD, 256, 0, stream>>>(qkvb, rpb + l * 4 * 169, abufA);
        // proj + residual + fused LN2 epilogue -> abufL
        k_gemm_ln<<<800, 256, 0, stream>>>(
            abufA, wtl + WT_PROJ, proj_b + l * 128, h,
            ln2_g + l * 128, ln2_b + l * 128, h, abufL, 128);
        // fc1: plain bf16-A GEMM
        k_gemm_mfma<64, 128, 32, 64, float><<<dim3(4, 400), 256, 0, stream>>>(
            abufL, wtl + WT_FC1, fc1_b + l * 512, nullptr, f1, 128, 512);
        k_dwconv<<<NIMG * HH * 2, 512, 0, stream>>>(f1, dw_w + l * 27 * 512, dw_b + l * 512, f2b);
        if (l == 0) {
            // fc2 + residual + fused LN1(layer 1) epilogue -> abufL
            k_gemm_ln<<<800, 256, 0, stream>>>(
                f2b, wtl + WT_FC2, fc2_b, h,
                ln1_g + 128, ln1_b + 128, h, abufL, 512);
        } else {
            // fc2 + residual + FINAL LN + transposed store
            k_gemm_lnout<<<800, 256, 0, stream>>>(
                f2b, wtl + WT_FC2, fc2_b + 128, h, out_g, out_b, out, 512);
        }
    }
}

// Round 13
// 410.233 us; speedup vs baseline: 1.4021x; 1.0220x over previous
//
#include <hip/hip_runtime.h>
#include <hip/hip_bf16.h>
#include <math.h>

typedef __hip_bfloat16 bf16;
typedef __attribute__((ext_vector_type(8))) short short8;
typedef __attribute__((ext_vector_type(4))) float floatx4;
typedef _Float16 h2 __attribute__((ext_vector_type(2)));

#define HH 40
#define WW 40
#define CC 128
#define TT 8
#define NIMG 16           // B*T
#define NTOK 25600        // NIMG*HH*WW
#define MDIM 512
#define NHEAD 4
#define KVP 1608          // K/V LDS plane stride in elems

// weight-transpose buffer offsets (bf16 elems), per layer
#define WT_QKV 0
#define WT_PROJ 49152
#define WT_FC1  65536
#define WT_FC2  131072
#define WT_L    196608

// ---- input transpose via LDS tiles: x (b,c,t,y,x) -> h (n,y,x,c), both coalesced.
__global__ __launch_bounds__(256) void k_transpose_in(const float* __restrict__ x,
                                                      float* __restrict__ h) {
    int blk = blockIdx.x;
    int n = blk / 200; int r = blk % 200; int ci = r / 50, ri = r % 50;
    int b = n >> 3, t = n & 7;
    int c0 = ci * 32, r0 = ri * 32;
    __shared__ float tile[32][33];
    int tid = threadIdx.x;
    int lc = tid >> 5, lr = tid & 31;         // 8 x 32
    #pragma unroll
    for (int it = 0; it < 4; ++it) {
        int cc = it * 8 + lc;
        tile[cc][lr] = x[((size_t)((b * 128 + c0 + cc) * 8 + t)) * 1600 + r0 + lr];
    }
    __syncthreads();
    #pragma unroll
    for (int it = 0; it < 4; ++it) {
        int rr = it * 8 + lc;
        h[((size_t)(n * 1600 + r0 + rr)) * 128 + c0 + lr] = tile[lr][rr];
    }
}

// ---- weight convert+transpose: W[K,N] fp32 -> Wt[N,K] bf16, 64x64 LDS tiles.
__global__ __launch_bounds__(256) void k_wt(const float* __restrict__ qkv_w,
                                            const float* __restrict__ proj_w,
                                            const float* __restrict__ fc1_w,
                                            const float* __restrict__ fc2_w,
                                            bf16* __restrict__ wt) {
    __shared__ float tile[64][65];
    int id = blockIdx.x;
    int l = id / 48, r = id % 48;
    const float* src; bf16* dst; int K_, N_, t;
    if (r < 12)      { src = qkv_w  + l * 128 * 384; dst = wt + l * WT_L + WT_QKV; K_ = 128; N_ = 384; t = r; }
    else if (r < 16) { src = proj_w + l * 128 * 128; dst = wt + l * WT_L + WT_PROJ; K_ = 128; N_ = 128; t = r - 12; }
    else if (r < 32) { src = fc1_w  + l * 128 * 512; dst = wt + l * WT_L + WT_FC1; K_ = 128; N_ = 512; t = r - 16; }
    else             { src = fc2_w  + l * 512 * 128; dst = wt + l * WT_L + WT_FC2; K_ = 512; N_ = 128; t = r - 32; }
    int KT = K_ >> 6;
    int k0 = (t % KT) * 64, n0 = (t / KT) * 64;
    int tid = threadIdx.x;
    for (int c = tid; c < 4096; c += 256) {
        int kk = c >> 6, nn = c & 63;
        tile[kk][nn] = src[(size_t)(k0 + kk) * N_ + n0 + nn];
    }
    __syncthreads();
    for (int c = tid; c < 4096; c += 256) {
        int nn = c >> 6, kk = c & 63;
        dst[(size_t)(n0 + nn) * K_ + k0 + kk] = __float2bfloat16(tile[kk][nn]);
    }
}

// ---- fused LayerNorm + MFMA GEMM (fp32 A): only layer-0 qkv.
template<typename OutT>
__global__ __launch_bounds__(256) void k_lngemm(const float* __restrict__ A,
                                                const bf16* __restrict__ Bt,
                                                const float* __restrict__ g,
                                                const float* __restrict__ be,
                                                const float* __restrict__ bias,
                                                OutT* __restrict__ D,
                                                int N) {
    constexpr int LDK = 40;
    __shared__ bf16 As[64 * LDK];
    __shared__ bf16 Bs[128 * LDK];
    __shared__ float sMean[64], sRstd[64], sG[128], sB[128];
    int tid = threadIdx.x;
    int m0 = blockIdx.y * 64, n0 = blockIdx.x * 128;
    {
        int row = tid >> 2, q4 = tid & 3;
        const float* p = A + (size_t)(m0 + row) * 128 + q4 * 32;
        float s = 0.f, q = 0.f;
        #pragma unroll
        for (int i = 0; i < 32; i += 4) {
            float4 f = *(const float4*)(p + i);
            s += f.x + f.y + f.z + f.w;
            q += f.x * f.x + f.y * f.y + f.z * f.z + f.w * f.w;
        }
        s += __shfl_xor(s, 1); q += __shfl_xor(q, 1);
        s += __shfl_xor(s, 2); q += __shfl_xor(q, 2);
        if (q4 == 0) {
            float mean = s * (1.0f / 128.0f);
            float var = q * (1.0f / 128.0f) - mean * mean;
            sMean[row] = mean;
            sRstd[row] = rsqrtf(var + 1e-5f);
        }
        if (tid < 128) { sG[tid] = g[tid]; sB[tid] = be[tid]; }
    }
    __syncthreads();
    int wave = tid >> 6, lane = tid & 63;
    int l15 = lane & 15, quad = lane >> 4;
    int wr = wave >> 1, wc = wave & 1;
    floatx4 acc[2][4];
    #pragma unroll
    for (int i = 0; i < 2; ++i)
        #pragma unroll
        for (int j = 0; j < 4; ++j)
            acc[i][j] = (floatx4){0.f, 0.f, 0.f, 0.f};

    for (int k0 = 0; k0 < 128; k0 += 32) {
        #pragma unroll
        for (int it = 0; it < 2; ++it) {
            int c = tid + it * 256;
            int row = c >> 3, kq = (c & 7) * 4;
            float4 f = *(const float4*)(A + (size_t)(m0 + row) * 128 + k0 + kq);
            float mean = sMean[row], rst = sRstd[row];
            float r0v = (f.x - mean) * rst * sG[k0 + kq]     + sB[k0 + kq];
            float r1v = (f.y - mean) * rst * sG[k0 + kq + 1] + sB[k0 + kq + 1];
            float r2v = (f.z - mean) * rst * sG[k0 + kq + 2] + sB[k0 + kq + 2];
            float r3v = (f.w - mean) * rst * sG[k0 + kq + 3] + sB[k0 + kq + 3];
            __hip_bfloat162 p0, p1;
            p0.x = __float2bfloat16(r0v); p0.y = __float2bfloat16(r1v);
            p1.x = __float2bfloat16(r2v); p1.y = __float2bfloat16(r3v);
            *(__hip_bfloat162*)&As[row * LDK + kq]     = p0;
            *(__hip_bfloat162*)&As[row * LDK + kq + 2] = p1;
        }
        #pragma unroll
        for (int c = tid; c < 512; c += 256) {
            int row = c >> 2, off = (c & 3) * 8;
            *(uint4*)&Bs[row * LDK + off] =
                *(const uint4*)&Bt[(size_t)(n0 + row) * 128 + k0 + off];
        }
        __syncthreads();
        short8 af[2], bfr[4];
        #pragma unroll
        for (int i = 0; i < 2; ++i)
            af[i] = *(const short8*)&As[(wr * 32 + i * 16 + l15) * LDK + quad * 8];
        #pragma unroll
        for (int j = 0; j < 4; ++j)
            bfr[j] = *(const short8*)&Bs[(wc * 64 + j * 16 + l15) * LDK + quad * 8];
        #pragma unroll
        for (int i = 0; i < 2; ++i)
            #pragma unroll
            for (int j = 0; j < 4; ++j)
                acc[i][j] = __builtin_amdgcn_mfma_f32_16x16x32_bf16(af[i], bfr[j], acc[i][j], 0, 0, 0);
        __syncthreads();
    }
    #pragma unroll
    for (int i = 0; i < 2; ++i) {
        #pragma unroll
        for (int j = 0; j < 4; ++j) {
            int nn = n0 + wc * 64 + j * 16 + l15;
            float bv = bias[nn];
            #pragma unroll
            for (int rg = 0; rg < 4; ++rg) {
                int m = m0 + wr * 32 + i * 16 + quad * 4 + rg;
                float v = acc[i][j][rg] + bv;
                if constexpr (sizeof(OutT) == 2)
                    D[(size_t)m * N + nn] = __float2bfloat16(v);
                else
                    D[(size_t)m * N + nn] = v;
            }
        }
    }
}

// ---- MFMA bf16 GEMM: D[M,N] = A[M,K] @ Bt[N,K]^T + bias (+R).
template<int BM, int BN, int WM, int WN, typename OutT>
__global__ __launch_bounds__(256) void k_gemm_mfma(const bf16* __restrict__ A,
                                                   const bf16* __restrict__ Bt,
                                                   const float* __restrict__ bias,
                                                   const float* __restrict__ R,
                                                   OutT* __restrict__ D,
                                                   int K, int N) {
    constexpr int LDK = 40;
    __shared__ bf16 As[BM * LDK];
    __shared__ bf16 Bs[BN * LDK];
    int tid = threadIdx.x;
    int wave = tid >> 6, lane = tid & 63;
    int l15 = lane & 15, quad = lane >> 4;
    constexpr int WCOLS = BN / WN;
    int wr = wave / WCOLS, wc = wave % WCOLS;
    int m0 = blockIdx.y * BM, n0 = blockIdx.x * BN;
    constexpr int MI = WM / 16, NJ = WN / 16;
    floatx4 acc[MI][NJ];
    #pragma unroll
    for (int i = 0; i < MI; ++i)
        #pragma unroll
        for (int j = 0; j < NJ; ++j)
            acc[i][j] = (floatx4){0.f, 0.f, 0.f, 0.f};

    for (int k0 = 0; k0 < K; k0 += 32) {
        #pragma unroll
        for (int c = tid; c < BM * 4; c += 256) {
            int row = c >> 2, off = (c & 3) * 8;
            *(uint4*)&As[row * LDK + off] =
                *(const uint4*)&A[(size_t)(m0 + row) * K + k0 + off];
        }
        #pragma unroll
        for (int c = tid; c < BN * 4; c += 256) {
            int row = c >> 2, off = (c & 3) * 8;
            *(uint4*)&Bs[row * LDK + off] =
                *(const uint4*)&Bt[(size_t)(n0 + row) * K + k0 + off];
        }
        __syncthreads();
        short8 af[MI], bfr[NJ];
        #pragma unroll
        for (int i = 0; i < MI; ++i)
            af[i] = *(const short8*)&As[(wr * WM + i * 16 + l15) * LDK + quad * 8];
        #pragma unroll
        for (int j = 0; j < NJ; ++j)
            bfr[j] = *(const short8*)&Bs[(wc * WN + j * 16 + l15) * LDK + quad * 8];
        #pragma unroll
        for (int i = 0; i < MI; ++i)
            #pragma unroll
            for (int j = 0; j < NJ; ++j)
                acc[i][j] = __builtin_amdgcn_mfma_f32_16x16x32_bf16(af[i], bfr[j], acc[i][j], 0, 0, 0);
        __syncthreads();
    }
    #pragma unroll
    for (int i = 0; i < MI; ++i) {
        #pragma unroll
        for (int j = 0; j < NJ; ++j) {
            int nn = n0 + wc * WN + j * 16 + l15;
            float bv = bias[nn];
            #pragma unroll
            for (int rg = 0; rg < 4; ++rg) {
                int m = m0 + wr * WM + i * 16 + quad * 4 + rg;
                float v = acc[i][j][rg] + bv;
                if (R) v += R[(size_t)m * N + nn];
                if constexpr (sizeof(OutT) == 2)
                    D[(size_t)m * N + nn] = __float2bfloat16(v);
                else
                    D[(size_t)m * N + nn] = v;
            }
        }
    }
}

// ---- GEMM (N=128) + residual + fused next-LayerNorm epilogue.
__global__ __launch_bounds__(256) void k_gemm_ln(const bf16* __restrict__ A,
                                                 const bf16* __restrict__ Bt,
                                                 const float* __restrict__ bias,
                                                 const float* __restrict__ R,
                                                 const float* __restrict__ g,
                                                 const float* __restrict__ be,
                                                 float* __restrict__ Dres,
                                                 bf16* __restrict__ Aout,
                                                 int K) {
    constexpr int LDK = 40;
    __shared__ bf16 As[32 * LDK];
    __shared__ bf16 Bs[128 * LDK];
    __shared__ float ot[32][132];
    __shared__ float sG[128], sB[128];
    int tid = threadIdx.x;
    int wave = tid >> 6, lane = tid & 63;
    int l15 = lane & 15, quad = lane >> 4;
    int wr = wave >> 1, wc = wave & 1;
    int m0 = blockIdx.x * 32;
    if (tid < 128) { sG[tid] = g[tid]; sB[tid] = be[tid]; }
    floatx4 acc[4];
    #pragma unroll
    for (int j = 0; j < 4; ++j) acc[j] = (floatx4){0.f, 0.f, 0.f, 0.f};

    for (int k0 = 0; k0 < K; k0 += 32) {
        if (tid < 128) {
            int row = tid >> 2, off = (tid & 3) * 8;
            *(uint4*)&As[row * LDK + off] =
                *(const uint4*)&A[(size_t)(m0 + row) * K + k0 + off];
        }
        #pragma unroll
        for (int c = tid; c < 512; c += 256) {
            int row = c >> 2, off = (c & 3) * 8;
            *(uint4*)&Bs[row * LDK + off] =
                *(const uint4*)&Bt[(size_t)row * K + k0 + off];
        }
        __syncthreads();
        short8 af = *(const short8*)&As[(wr * 16 + l15) * LDK + quad * 8];
        short8 bfr[4];
        #pragma unroll
        for (int j = 0; j < 4; ++j)
            bfr[j] = *(const short8*)&Bs[(wc * 64 + j * 16 + l15) * LDK + quad * 8];
        #pragma unroll
        for (int j = 0; j < 4; ++j)
            acc[j] = __builtin_amdgcn_mfma_f32_16x16x32_bf16(af, bfr[j], acc[j], 0, 0, 0);
        __syncthreads();
    }
    #pragma unroll
    for (int j = 0; j < 4; ++j) {
        int nn = wc * 64 + j * 16 + l15;
        float bv = bias[nn];
        #pragma unroll
        for (int rg = 0; rg < 4; ++rg) {
            int m = wr * 16 + quad * 4 + rg;
            ot[m][nn] = acc[j][rg] + bv + R[(size_t)(m0 + m) * 128 + nn];
        }
    }
    __syncthreads();
    int row = tid >> 3, sub = tid & 7;
    float vv[16];
    float s = 0.f, q = 0.f;
    #pragma unroll
    for (int i = 0; i < 16; ++i) {
        float v = ot[row][sub * 16 + i];
        vv[i] = v; s += v; q += v * v;
    }
    #pragma unroll
    for (int o = 4; o > 0; o >>= 1) { s += __shfl_xor(s, o); q += __shfl_xor(q, o); }
    float mean = s * (1.0f / 128.0f);
    float var = q * (1.0f / 128.0f) - mean * mean;
    float rst = rsqrtf(var + 1e-5f);
    size_t base = (size_t)(m0 + row) * 128 + sub * 16;
    #pragma unroll
    for (int i = 0; i < 16; i += 4)
        *(float4*)(Dres + base + i) = (float4){vv[i], vv[i+1], vv[i+2], vv[i+3]};
    #pragma unroll
    for (int i = 0; i < 16; i += 2) {
        int ch = sub * 16 + i;
        __hip_bfloat162 o2;
        o2.x = __float2bfloat16((vv[i]     - mean) * rst * sG[ch]     + sB[ch]);
        o2.y = __float2bfloat16((vv[i + 1] - mean) * rst * sG[ch + 1] + sB[ch + 1]);
        *(__hip_bfloat162*)(Aout + base + i) = o2;
    }
}

// ---- GEMM (N=128) + residual + FINAL LayerNorm + transposed store to (b,c,t,y,x).
__global__ __launch_bounds__(256) void k_gemm_lnout(const bf16* __restrict__ A,
                                                    const bf16* __restrict__ Bt,
                                                    const float* __restrict__ bias,
                                                    const float* __restrict__ R,
                                                    const float* __restrict__ g,
                                                    const float* __restrict__ be,
                                                    float* __restrict__ out,
                                                    int K) {
    constexpr int LDK = 40;
    __shared__ bf16 As[32 * LDK];
    __shared__ bf16 Bs[128 * LDK];
    __shared__ float ot[32][133];    // pad 133: conflict-free transposed reads
    __shared__ float sG[128], sB[128];
    int tid = threadIdx.x;
    int wave = tid >> 6, lane = tid & 63;
    int l15 = lane & 15, quad = lane >> 4;
    int wr = wave >> 1, wc = wave & 1;
    int m0 = blockIdx.x * 32;
    if (tid < 128) { sG[tid] = g[tid]; sB[tid] = be[tid]; }
    floatx4 acc[4];
    #pragma unroll
    for (int j = 0; j < 4; ++j) acc[j] = (floatx4){0.f, 0.f, 0.f, 0.f};

    for (int k0 = 0; k0 < K; k0 += 32) {
        if (tid < 128) {
            int row = tid >> 2, off = (tid & 3) * 8;
            *(uint4*)&As[row * LDK + off] =
                *(const uint4*)&A[(size_t)(m0 + row) * K + k0 + off];
        }
        #pragma unroll
        for (int c = tid; c < 512; c += 256) {
            int row = c >> 2, off = (c & 3) * 8;
            *(uint4*)&Bs[row * LDK + off] =
                *(const uint4*)&Bt[(size_t)row * K + k0 + off];
        }
        __syncthreads();
        short8 af = *(const short8*)&As[(wr * 16 + l15) * LDK + quad * 8];
        short8 bfr[4];
        #pragma unroll
        for (int j = 0; j < 4; ++j)
            bfr[j] = *(const short8*)&Bs[(wc * 64 + j * 16 + l15) * LDK + quad * 8];
        #pragma unroll
        for (int j = 0; j < 4; ++j)
            acc[j] = __builtin_amdgcn_mfma_f32_16x16x32_bf16(af, bfr[j], acc[j], 0, 0, 0);
        __syncthreads();
    }
    #pragma unroll
    for (int j = 0; j < 4; ++j) {
        int nn = wc * 64 + j * 16 + l15;
        float bv = bias[nn];
        #pragma unroll
        for (int rg = 0; rg < 4; ++rg) {
            int m = wr * 16 + quad * 4 + rg;
            ot[m][nn] = acc[j][rg] + bv + R[(size_t)(m0 + m) * 128 + nn];
        }
    }
    __syncthreads();
    int row = tid >> 3, sub = tid & 7;
    float vv[16];
    float s = 0.f, q = 0.f;
    #pragma unroll
    for (int i = 0; i < 16; ++i) {
        float v = ot[row][sub * 16 + i];
        vv[i] = v; s += v; q += v * v;
    }
    #pragma unroll
    for (int o = 4; o > 0; o >>= 1) { s += __shfl_xor(s, o); q += __shfl_xor(q, o); }
    float mean = s * (1.0f / 128.0f);
    float var = q * (1.0f / 128.0f) - mean * mean;
    float rst = rsqrtf(var + 1e-5f);
    #pragma unroll
    for (int i = 0; i < 16; ++i) {
        int ch = sub * 16 + i;
        ot[row][ch] = (vv[i] - mean) * rst * sG[ch] + sB[ch];
    }
    __syncthreads();
    int n = m0 / 1600, rem0 = m0 % 1600;
    int b = n >> 3, t = n & 7;
    #pragma unroll
    for (int it = 0; it < 16; ++it) {
        int idx = it * 256 + tid;
        int ch = idx >> 5, tk = idx & 31;
        out[((size_t)((b * 128 + ch) * 8 + t)) * 1600 + rem0 + tk] = ot[tk][ch];
    }
}

// ---- row-tiled 7x7 neighborhood attention; f16 K + fdot2 logits, q in LDS (f16).
// XCD-locality swizzle: same-XCD blocks get consecutive y (shared K/V windows).
__global__ __launch_bounds__(256) void k_attn(const bf16* __restrict__ qkv,
                                              const float* __restrict__ rpb,
                                              bf16* __restrict__ out) {
    int raw = blockIdx.x;                       // grid 2560
    int blk = (raw & 7) * 320 + (raw >> 3);     // chunk per XCD
    int head = blk & 3;
    int ny = blk >> 2;
    int n = ny / 40, y = ny % 40;
    int sy = min(max(y - 3, 0), HH - 7);
    __shared__ __align__(16) short KVs[7 * KVP];   // K (f16) then V (bf16)
    __shared__ __align__(16) short qs[40 * 40];    // q as f16, stride 40 (3.2 KB)
    __shared__ float lg[40][49];
    int tid = threadIdx.x;
    // q staging: bf16 -> f16, 160 threads x 8 elems
    if (tid < 160) {
        int xq = tid >> 2, d8 = (tid & 3) * 8;
        union { uint4 u; __hip_bfloat162 b[4]; } U;
        U.u = *(const uint4*)(qkv + ((size_t)(n * 1600 + y * 40 + xq)) * 384 + head * 32 + d8);
        union { short8 s; h2 h[4]; } W;
        #pragma unroll
        for (int c = 0; c < 4; ++c) {
            float2 f = __bfloat1622float2(U.b[c]);
            W.h[c].x = (_Float16)f.x; W.h[c].y = (_Float16)f.y;
        }
        *(short8*)&qs[xq * 40 + d8] = W.s;
    }
    // phase 1: K window, bf16 -> f16 in staging
    for (int i2 = tid; i2 < 1120; i2 += 256) {
        int d8 = i2 & 3, kx = (i2 >> 2) % 40, ky = i2 / 160;
        size_t base = ((size_t)(n * 1600 + (sy + ky) * 40 + kx)) * 384 + 128 + head * 32 + d8 * 8;
        union { uint4 u; __hip_bfloat162 b[4]; } U;
        U.u = *(const uint4*)(qkv + base);
        union { short8 s; h2 h[4]; } W;
        #pragma unroll
        for (int c = 0; c < 4; ++c) {
            float2 f = __bfloat1622float2(U.b[c]);
            W.h[c].x = (_Float16)f.x; W.h[c].y = (_Float16)f.y;
        }
        *(short8*)&KVs[ky * KVP + kx * 40 + d8 * 8] = W.s;
    }
    __syncthreads();
    // logits: thread per (xq, ky); q read from LDS as f16
    for (int p2 = tid; p2 < 280; p2 += 256) {
        int xq = p2 / 7, ky = p2 - (p2 / 7) * 7;
        int sx = min(max(xq - 3, 0), WW - 7);
        const h2* qp = (const h2*)&qs[xq * 40];
        h2 qh[16];
        #pragma unroll
        for (int c = 0; c < 16; ++c) qh[c] = qp[c];
        const float* rb = rpb + head * 169 + (sy + ky - y + 6) * 13 + (sx - xq + 6);
        int kbase = ky * KVP + sx * 40;
        #pragma unroll
        for (int jx = 0; jx < 7; ++jx) {
            const h2* kp = (const h2*)&KVs[kbase + jx * 40];
            float dot = 0.f;
            #pragma unroll
            for (int c = 0; c < 16; ++c)
                dot = __builtin_amdgcn_fdot2(qh[c], kp[c], dot, false);
            lg[xq][ky * 7 + jx] = dot * 0.1767766952966369f + rb[jx];
        }
    }
    __syncthreads();
    // phase 2: V window (raw bf16 bits), softmax concurrently
    for (int i2 = tid; i2 < 1120; i2 += 256) {
        int d8 = i2 & 3, kx = (i2 >> 2) % 40, ky = i2 / 160;
        size_t base = ((size_t)(n * 1600 + (sy + ky) * 40 + kx)) * 384 + 256 + head * 32 + d8 * 8;
        *(uint4*)&KVs[ky * KVP + kx * 40 + d8 * 8] = *(const uint4*)(qkv + base);
    }
    if (tid < 40) {
        float m = -1e30f;
        for (int j = 0; j < 49; ++j) m = fmaxf(m, lg[tid][j]);
        float s = 0.f;
        for (int j = 0; j < 49; ++j) { float e = expf(lg[tid][j] - m); lg[tid][j] = e; s += e; }
        float inv = 1.0f / s;
        for (int j = 0; j < 49; ++j) lg[tid][j] *= inv;
    }
    __syncthreads();
    for (int o = tid; o < 640; o += 256) {         // PV reduce (bf16 V)
        int xq = o >> 4, dp = (o & 15) * 2;
        int sx = min(max(xq - 3, 0), WW - 7);
        float a0 = 0.f, a1 = 0.f;
        #pragma unroll
        for (int ky = 0; ky < 7; ++ky) {
            int vbase = ky * KVP + sx * 40 + dp;
            #pragma unroll
            for (int jx = 0; jx < 7; ++jx) {
                float p = lg[xq][ky * 7 + jx];
                float2 v = __bfloat1622float2(*(const __hip_bfloat162*)&KVs[vbase + jx * 40]);
                a0 += p * v.x; a1 += p * v.y;
            }
        }
        __hip_bfloat162 o2;
        o2.x = __float2bfloat16(a0); o2.y = __float2bfloat16(a1);
        *(__hip_bfloat162*)(out + ((size_t)(n * 1600 + y * 40 + xq)) * 128 + head * 32 + dp) = o2;
    }
}

// ---- depthwise 3x3x3 conv + bias + exact GELU; fp32 in, bf16 out.
// XCD-locality swizzle: same-XCD blocks get consecutive (n,y) chunks (shared rows).
__global__ __launch_bounds__(512) void k_dwconv(const float* __restrict__ inp,
                                                const float* __restrict__ w,
                                                const float* __restrict__ bias,
                                                bf16* __restrict__ outp) {
    int raw = blockIdx.x;                       // grid 1280
    int blk = (raw & 7) * 160 + (raw >> 3);     // chunk per XCD
    int xh = blk & 1;
    int ny = blk >> 1;
    int n = ny / 40, y = ny - n * 40;
    int b = n >> 3, t = n & 7;
    int m = threadIdx.x;
    float wr[27];
    #pragma unroll
    for (int i = 0; i < 27; ++i) wr[i] = w[i * 512 + m];
    float bs = bias[m];
    const float* rp[9];
    #pragma unroll
    for (int dt = 0; dt < 3; ++dt)
        #pragma unroll
        for (int dy = 0; dy < 3; ++dy) {
            int tt = t + dt - 1, yy = y + dy - 1;
            bool v = (tt >= 0 && tt < 8 && yy >= 0 && yy < 40);
            rp[dt * 3 + dy] = v ? inp + ((size_t)((b * 8 + tt) * 1600 + yy * 40)) * 512 + m
                                : nullptr;
        }
    int x0 = xh * 20;
    float c0[9], c1[9], c2[9];
    #pragma unroll
    for (int p = 0; p < 9; ++p) {
        c0[p] = (x0 > 0 && rp[p]) ? rp[p][(size_t)(x0 - 1) * 512] : 0.f;
        c1[p] = rp[p] ? rp[p][(size_t)x0 * 512] : 0.f;
    }
    size_t outbase = ((size_t)(n * 1600 + y * 40)) * 512 + m;
    for (int x = x0; x < x0 + 20; ++x) {
        #pragma unroll
        for (int p = 0; p < 9; ++p)
            c2[p] = (x < 39 && rp[p]) ? rp[p][(size_t)(x + 1) * 512] : 0.f;
        float acc = bs;
        #pragma unroll
        for (int p = 0; p < 9; ++p)
            acc += wr[p * 3 + 0] * c0[p] + wr[p * 3 + 1] * c1[p] + wr[p * 3 + 2] * c2[p];
        float g = 0.5f * acc * (1.0f + erff(acc * 0.70710678118654752f));
        outp[outbase + (size_t)x * 512] = __float2bfloat16(g);
        #pragma unroll
        for (int p = 0; p < 9; ++p) { c0[p] = c1[p]; c1[p] = c2[p]; }
    }
}

extern "C" void kernel_launch(void* const* d_in, const int* in_sizes, int n_in,
                              void* d_out, int out_size, void* d_ws, size_t ws_size,
                              hipStream_t stream) {
    const float* x      = (const float*)d_in[0];
    const float* ln1_g  = (const float*)d_in[1];
    const float* ln1_b  = (const float*)d_in[2];
    const float* qkv_w  = (const float*)d_in[3];
    const float* qkv_b  = (const float*)d_in[4];
    const float* rpb    = (const float*)d_in[5];
    const float* proj_w = (const float*)d_in[6];
    const float* proj_b = (const float*)d_in[7];
    const float* ln2_g  = (const float*)d_in[8];
    const float* ln2_b  = (const float*)d_in[9];
    const float* fc1_w  = (const float*)d_in[10];
    const float* fc1_b  = (const float*)d_in[11];
    const float* dw_w   = (const float*)d_in[12];
    const float* dw_b   = (const float*)d_in[13];
    const float* fc2_w  = (const float*)d_in[14];
    const float* fc2_b  = (const float*)d_in[15];
    const float* out_g  = (const float*)d_in[16];
    const float* out_b  = (const float*)d_in[17];
    float* out = (float*)d_out;

    // workspace: h f32 | f1 f32 | qkvb bf16 | f2b bf16 | abufA bf16 | abufL bf16 | wt
    float* h     = (float*)d_ws;
    float* f1    = h + (size_t)NTOK * 128;
    bf16* qkvb   = (bf16*)(f1 + (size_t)NTOK * 512);
    bf16* f2b    = qkvb + (size_t)NTOK * 384;
    bf16* abufA  = f2b  + (size_t)NTOK * 512;
    bf16* abufL  = abufA + (size_t)NTOK * 128;
    bf16* wt     = abufL + (size_t)NTOK * 128;

    k_wt<<<96, 256, 0, stream>>>(qkv_w, proj_w, fc1_w, fc2_w, wt);
    k_transpose_in<<<NIMG * 200, 256, 0, stream>>>(x, h);
    for (int l = 0; l < 2; ++l) {
        const bf16* wtl = wt + (size_t)l * WT_L;
        if (l == 0) {
            k_lngemm<bf16><<<dim3(3, 400), 256, 0, stream>>>(
                h, wtl + WT_QKV, ln1_g, ln1_b, qkv_b, qkvb, 384);
        } else {
            k_gemm_mfma<64, 128, 32, 64, bf16><<<dim3(3, 400), 256, 0, stream>>>(
                abufL, wtl + WT_QKV, qkv_b + 384, nullptr, qkvb, 128, 384);
        }
        k_attn<<<NIMG * HH * NHEAD, 256, 0, stream>>>(qkvb, rpb + l * 4 * 169, abufA);
        // proj + residual + fused LN2 epilogue -> abufL
        k_gemm_ln<<<800, 256, 0, stream>>>(
            abufA, wtl + WT_PROJ, proj_b + l * 128, h,
            ln2_g + l * 128, ln2_b + l * 128, h, abufL, 128);
        // fc1: plain bf16-A GEMM
        k_gemm_mfma<64, 128, 32, 64, float><<<dim3(4, 400), 256, 0, stream>>>(
            abufL, wtl + WT_FC1, fc1_b + l * 512, nullptr, f1, 128, 512);
        k_dwconv<<<NIMG * HH * 2, 512, 0, stream>>>(f1, dw_w + l * 27 * 512, dw_b + l * 512, f2b);
        if (l == 0) {
            // fc2 + residual + fused LN1(layer 1) epilogue -> abufL
            k_gemm_ln<<<800, 256, 0, stream>>>(
                f2b, wtl + WT_FC2, fc2_b, h,
                ln1_g + 128, ln1_b + 128, h, abufL, 512);
        } else {
            // fc2 + residual + FINAL LN + transposed store
            k_gemm_lnout<<<800, 256, 0, stream>>>(
                f2b, wtl + WT_FC2, fc2_b + 128, h, out_g, out_b, out, 512);
        }
    }
}